// Round 1
// baseline (6538.203 us; speedup 1.0000x reference)
//
#include <hip/hip_runtime.h>
#include <math.h>

// ---------------- problem constants ----------------
#define N_NODES 100000
#define BATCH   2000
#define KNBR    20
#define DF      172      // D
#define MSGD    688      // 2D + D + T
#define M3      6000     // 3*B query rows
#define DH      86       // head dim (2 heads)
#define KIN_D   516      // D + D + T  (k_in width)

// GRU combined GEMM: C(N x 688) = [messages|memory](N x 860) @ W'^T
#define KA      864      // padded K (860 -> 864)
#define KA_REAL 860
#define NCOLP   704      // padded out cols (688 -> 704)

// ---------------- ws layout (floats) ----------------
#define WP_OFF  0
#define WP_SZ   (NCOLP * KA)            // 608256
#define BP_OFF  (WP_OFF + WP_SZ)
#define BP_SZ   NCOLP
#define MU_OFF  (BP_OFF + BP_SZ)        // 608960
#define MU_SZ   (N_NODES * DF)          // 17.2M floats
#define EMB_OFF (MU_OFF + MU_SZ)        // + 6000*172

__device__ __forceinline__ float sigmoidf_(float x) { return 1.0f / (1.0f + expf(-x)); }

// ============================================================
// Kernel 0: build combined GRU weight W' (704 x 864) and bias' (704)
//  cols j<344   : [w_ih[j] | w_hh[j]]          (r,z: i+h summed)
//  cols 344..515: [w_ih[j] | 0]                (i_n)
//  cols 516..687: [0       | w_hh[j-172]]      (h_n)
// ============================================================
__global__ __launch_bounds__(256) void prep_kernel(
    const float* __restrict__ w_ih, const float* __restrict__ w_hh,
    const float* __restrict__ b_ih, const float* __restrict__ b_hh,
    float* __restrict__ wp, float* __restrict__ bp)
{
    int idx = blockIdx.x * 256 + threadIdx.x;
    if (idx < NCOLP * KA) {
        int j = idx / KA, k = idx % KA;
        float v = 0.f;
        if (j < 344) {
            if (k < MSGD) v = w_ih[j * MSGD + k];
            else if (k < KA_REAL) v = w_hh[j * DF + (k - MSGD)];
        } else if (j < 516) {
            if (k < MSGD) v = w_ih[j * MSGD + k];
        } else if (j < 688) {
            if (k >= MSGD && k < KA_REAL) v = w_hh[(j - 172) * DF + (k - MSGD)];
        }
        wp[idx] = v;
    }
    if (idx < NCOLP) {
        float b = 0.f;
        if (idx < 344) b = b_ih[idx] + b_hh[idx];
        else if (idx < 516) b = b_ih[idx];
        else if (idx < 688) b = b_hh[idx - 172];
        bp[idx] = b;
    }
}

// ============================================================
// Kernel 1: GRU GEMM + fused epilogue
//  BM=16 rows/block, all 704 cols, BK=16. 256 thr: 4 rows x 11 cols each.
//  LDS: B tile (16x705) unioned with C stage (16x704), A tile 16x17.
// ============================================================
__global__ __launch_bounds__(256) void gru_kernel(
    const float* __restrict__ messages, const float* __restrict__ memory,
    const float* __restrict__ wp, const float* __restrict__ bp,
    float* __restrict__ mem_upd)
{
    __shared__ float Bs[16 * 705];   // B tile during main loop; C stage after
    __shared__ float As[16][17];
    const int t  = threadIdx.x;
    const int tx = t & 63, ty = t >> 6;
    const int row0 = blockIdx.x * 16;

    float acc[4][11];
#pragma unroll
    for (int r = 0; r < 4; ++r)
#pragma unroll
        for (int i = 0; i < 11; ++i) acc[r][i] = 0.f;

    const int ar = t >> 4, ak = t & 15;          // A-load: row, k
    const int bj0 = t >> 2, bk0 = (t & 3) << 2;  // B-load: col base, k base

    for (int k0 = 0; k0 < KA; k0 += 16) {
        { // A tile: [messages | memory | 0]
            int gk = k0 + ak;
            int grow = row0 + ar;   // N = 6250*16 exactly, no guard needed
            float v;
            if (gk < MSGD) v = messages[grow * MSGD + gk];
            else if (gk < KA_REAL) v = memory[grow * DF + (gk - MSGD)];
            else v = 0.f;
            As[ar][ak] = v;
        }
#pragma unroll
        for (int it = 0; it < 11; ++it) { // B tile, transposed into LDS
            int j = bj0 + (it << 6);
            const float4 w = *reinterpret_cast<const float4*>(&wp[j * KA + k0 + bk0]);
            Bs[(bk0 + 0) * 705 + j] = w.x;
            Bs[(bk0 + 1) * 705 + j] = w.y;
            Bs[(bk0 + 2) * 705 + j] = w.z;
            Bs[(bk0 + 3) * 705 + j] = w.w;
        }
        __syncthreads();
#pragma unroll
        for (int kk = 0; kk < 16; ++kk) {
            float a[4];
#pragma unroll
            for (int r = 0; r < 4; ++r) a[r] = As[ty * 4 + r][kk];
#pragma unroll
            for (int i = 0; i < 11; ++i) {
                float b = Bs[kk * 705 + tx + (i << 6)];
#pragma unroll
                for (int r = 0; r < 4; ++r) acc[r][i] = fmaf(a[r], b, acc[r][i]);
            }
        }
        __syncthreads();
    }

    // stage C tile into LDS (reuse Bs region)
#pragma unroll
    for (int r = 0; r < 4; ++r)
#pragma unroll
        for (int i = 0; i < 11; ++i)
            Bs[(ty * 4 + r) * 704 + tx + (i << 6)] = acc[r][i];
    __syncthreads();

    // fused GRU epilogue: 16 rows x 172 dims
    for (int idx = t; idx < 16 * DF; idx += 256) {
        int r = idx / DF, d = idx - r * DF;
        int grow = row0 + r;
        float sr  = Bs[r * 704 + d]       + bp[d];
        float sz  = Bs[r * 704 + d + 172] + bp[d + 172];
        float gin = Bs[r * 704 + d + 344] + bp[d + 344];
        float ghn = Bs[r * 704 + d + 516] + bp[d + 516];
        float mem = memory[grow * DF + d];
        float rg = sigmoidf_(sr);
        float zg = sigmoidf_(sz);
        float nt = tanhf(fmaf(rg, ghn, gin));
        mem_upd[grow * DF + d] = fmaf(zg, mem - nt, nt);  // (1-z)*n + z*m
    }
}

// ============================================================
// Kernel 2: per-query attention + merge MLP (one block per row, 6000 rows)
// ============================================================
__global__ __launch_bounds__(256) void attn_kernel(
    const float* __restrict__ mem_upd, const float* __restrict__ edge_features,
    const float* __restrict__ edge_times, const float* __restrict__ neighbor_times,
    const float* __restrict__ time_w, const float* __restrict__ time_b,
    const float* __restrict__ w_q, const float* __restrict__ w_k,
    const float* __restrict__ w_v, const float* __restrict__ w_o,
    const float* __restrict__ merge_w1, const float* __restrict__ merge_b1,
    const float* __restrict__ merge_w2, const float* __restrict__ merge_b2,
    const int* __restrict__ src_nodes, const int* __restrict__ dst_nodes,
    const int* __restrict__ neg_nodes, const int* __restrict__ neighbors,
    const int* __restrict__ nbr_eidx, float* __restrict__ emb)
{
    __shared__ __align__(16) float kin[KNBR][KIN_D];  // 41.3 KB
    __shared__ float kkl[KNBR][DF];                   // 13.8 KB
    __shared__ float sf[DF];
    __shared__ __align__(16) float qin[344];
    __shared__ float qv[DF];
    __shared__ float ctxl[DF];
    __shared__ float scl[2][KNBR];
    __shared__ float attnl[2][KNBR];
    __shared__ __align__(16) float catl[344];
    __shared__ float h1l[DF];
    __shared__ int   nbrs[KNBR];
    __shared__ int   eidxs[KNBR];
    __shared__ float dts[KNBR];

    const int i = blockIdx.x;
    const int t = threadIdx.x;

    int node;
    if (i < BATCH)          node = src_nodes[i];
    else if (i < 2 * BATCH) node = dst_nodes[i - BATCH];
    else                    node = neg_nodes[i - 2 * BATCH];
    const float tsv = edge_times[i % BATCH];

    if (t < KNBR) {
        nbrs[t]  = neighbors[i * KNBR + t];
        eidxs[t] = nbr_eidx[i * KNBR + t];
        dts[t]   = tsv - neighbor_times[i * KNBR + t];
    }
    if (t < DF) {
        float v = mem_upd[node * DF + t];
        sf[t] = v;
        qin[t] = v;
        qin[DF + t] = cosf(time_b[t]);   // time_enc(0)
    }
    __syncthreads();

    // q = q_in @ w_q^T
    if (t < DF) {
        float s = 0.f;
#pragma unroll 4
        for (int j = 0; j < 344; ++j) s = fmaf(qin[j], w_q[t * 344 + j], s);
        qv[t] = s;
    }
    // fill k_in (20 x 516): [nbr_feat | e_feat | time_enc(dt)]
    for (int idx = t; idx < KNBR * KIN_D; idx += 256) {
        int kn = idx / KIN_D, c = idx - kn * KIN_D;
        float v;
        if (c < DF)       v = mem_upd[nbrs[kn] * DF + c];
        else if (c < 344) v = edge_features[eidxs[kn] * DF + (c - DF)];
        else { int j = c - 344; v = cosf(fmaf(dts[kn], time_w[j], time_b[j])); }
        kin[kn][c] = v;
    }
    __syncthreads();

    // K,V projections: thread d owns output dim d for all 20 neighbors.
    float av[KNBR];
    if (t < DF) {
        float ak[KNBR];
#pragma unroll
        for (int kn = 0; kn < KNBR; ++kn) { ak[kn] = 0.f; av[kn] = 0.f; }
        const float4* wkp = reinterpret_cast<const float4*>(&w_k[t * KIN_D]);
        const float4* wvp = reinterpret_cast<const float4*>(&w_v[t * KIN_D]);
        for (int c4 = 0; c4 < KIN_D / 4; ++c4) {
            float4 wk = wkp[c4];
            float4 wv = wvp[c4];
#pragma unroll
            for (int kn = 0; kn < KNBR; ++kn) {
                float4 kv = *reinterpret_cast<const float4*>(&kin[kn][c4 * 4]);
                ak[kn] = fmaf(wk.x, kv.x, ak[kn]); ak[kn] = fmaf(wk.y, kv.y, ak[kn]);
                ak[kn] = fmaf(wk.z, kv.z, ak[kn]); ak[kn] = fmaf(wk.w, kv.w, ak[kn]);
                av[kn] = fmaf(wv.x, kv.x, av[kn]); av[kn] = fmaf(wv.y, kv.y, av[kn]);
                av[kn] = fmaf(wv.z, kv.z, av[kn]); av[kn] = fmaf(wv.w, kv.w, av[kn]);
            }
        }
#pragma unroll
        for (int kn = 0; kn < KNBR; ++kn) kkl[kn][t] = ak[kn];
    }
    __syncthreads();

    // scores (2 heads x 20 nbrs) + mask
    if (t < 2 * KNBR) {
        int h = t / KNBR, kn = t - h * KNBR;
        float s = 0.f;
#pragma unroll 2
        for (int j = 0; j < DH; ++j) s = fmaf(qv[h * DH + j], kkl[kn][h * DH + j], s);
        s /= sqrtf((float)DH);
        scl[h][kn] = (nbrs[kn] > 0) ? s : -1e9f;
    }
    __syncthreads();
    if (t < 2) {
        float m = -INFINITY;
        for (int kn = 0; kn < KNBR; ++kn) m = fmaxf(m, scl[t][kn]);
        float se = 0.f;
        for (int kn = 0; kn < KNBR; ++kn) se += expf(scl[t][kn] - m);
        float inv = 1.f / se;
        for (int kn = 0; kn < KNBR; ++kn) attnl[t][kn] = expf(scl[t][kn] - m) * inv;
    }
    __syncthreads();
    // ctx (V is still in registers per-thread)
    if (t < DF) {
        int h = t / DH;
        float cx = 0.f;
#pragma unroll
        for (int kn = 0; kn < KNBR; ++kn) cx = fmaf(attnl[h][kn], av[kn], cx);
        ctxl[t] = cx;
    }
    __syncthreads();
    // w_o projection, build concat [ctx_o | src_feat]
    if (t < DF) {
        float s = 0.f;
#pragma unroll 4
        for (int j = 0; j < DF; ++j) s = fmaf(ctxl[j], w_o[t * DF + j], s);
        catl[t] = s;
        catl[DF + t] = sf[t];
    }
    __syncthreads();
    if (t < DF) {
        float s = merge_b1[t];
#pragma unroll 4
        for (int j = 0; j < 344; ++j) s = fmaf(catl[j], merge_w1[t * 344 + j], s);
        h1l[t] = fmaxf(s, 0.f);
    }
    __syncthreads();
    if (t < DF) {
        float s = merge_b2[t];
#pragma unroll 4
        for (int j = 0; j < DF; ++j) s = fmaf(h1l[j], merge_w2[t * DF + j], s);
        emb[i * DF + t] = s;
    }
}

// ============================================================
// Kernel 3: affinity MLP -> sigmoid prob (4000 pairs)
// ============================================================
__global__ __launch_bounds__(256) void aff_kernel(
    const float* __restrict__ emb,
    const float* __restrict__ aff_w1, const float* __restrict__ aff_b1,
    const float* __restrict__ aff_w2, const float* __restrict__ aff_b2,
    float* __restrict__ out)
{
    __shared__ __align__(16) float pair[344];
    __shared__ float ahl[DF];
    __shared__ float red[4];
    const int j = blockIdx.x;
    const int t = threadIdx.x;
    const int s_idx = (j < BATCH) ? j : (j - BATCH);
    const int d_idx = (j < BATCH) ? (BATCH + j) : (2 * BATCH + (j - BATCH));
    if (t < DF) {
        pair[t]      = emb[s_idx * DF + t];
        pair[DF + t] = emb[d_idx * DF + t];
    }
    __syncthreads();
    if (t < DF) {
        float s = aff_b1[t];
#pragma unroll 4
        for (int c = 0; c < 344; ++c) s = fmaf(pair[c], aff_w1[t * 344 + c], s);
        ahl[t] = fmaxf(s, 0.f);
    }
    __syncthreads();
    float p = 0.f;
    if (t < DF) p = ahl[t] * aff_w2[t];
#pragma unroll
    for (int off = 32; off > 0; off >>= 1) p += __shfl_down(p, off, 64);
    if ((t & 63) == 0) red[t >> 6] = p;
    __syncthreads();
    if (t == 0) {
        float s = red[0] + red[1] + red[2] + red[3] + aff_b2[0];
        out[j] = 1.f / (1.f + expf(-s));
    }
}

// ============================================================
extern "C" void kernel_launch(void* const* d_in, const int* in_sizes, int n_in,
                              void* d_out, int out_size, void* d_ws, size_t ws_size,
                              hipStream_t stream)
{
    (void)in_sizes; (void)n_in; (void)out_size; (void)ws_size;
    const float* memory         = (const float*)d_in[0];
    const float* messages       = (const float*)d_in[1];
    const float* edge_features  = (const float*)d_in[2];
    const float* edge_times     = (const float*)d_in[3];
    const float* neighbor_times = (const float*)d_in[4];
    const float* time_w         = (const float*)d_in[5];
    const float* time_b         = (const float*)d_in[6];
    const float* gru_w_ih       = (const float*)d_in[7];
    const float* gru_w_hh       = (const float*)d_in[8];
    const float* gru_b_ih       = (const float*)d_in[9];
    const float* gru_b_hh       = (const float*)d_in[10];
    const float* w_q            = (const float*)d_in[11];
    const float* w_k            = (const float*)d_in[12];
    const float* w_v            = (const float*)d_in[13];
    const float* w_o            = (const float*)d_in[14];
    const float* merge_w1       = (const float*)d_in[15];
    const float* merge_b1       = (const float*)d_in[16];
    const float* merge_w2       = (const float*)d_in[17];
    const float* merge_b2       = (const float*)d_in[18];
    const float* aff_w1         = (const float*)d_in[19];
    const float* aff_b1         = (const float*)d_in[20];
    const float* aff_w2         = (const float*)d_in[21];
    const float* aff_b2         = (const float*)d_in[22];
    const int* src_nodes        = (const int*)d_in[23];
    const int* dst_nodes        = (const int*)d_in[24];
    const int* neg_nodes        = (const int*)d_in[25];
    const int* neighbors        = (const int*)d_in[26];
    const int* nbr_eidx         = (const int*)d_in[27];

    float* ws      = (float*)d_ws;
    float* wp      = ws + WP_OFF;
    float* bp      = ws + BP_OFF;
    float* mem_upd = ws + MU_OFF;
    float* emb     = ws + EMB_OFF;
    float* out     = (float*)d_out;

    prep_kernel<<<(NCOLP * KA + 255) / 256, 256, 0, stream>>>(
        gru_w_ih, gru_w_hh, gru_b_ih, gru_b_hh, wp, bp);
    gru_kernel<<<N_NODES / 16, 256, 0, stream>>>(messages, memory, wp, bp, mem_upd);
    attn_kernel<<<M3, 256, 0, stream>>>(mem_upd, edge_features, edge_times,
        neighbor_times, time_w, time_b, w_q, w_k, w_v, w_o,
        merge_w1, merge_b1, merge_w2, merge_b2,
        src_nodes, dst_nodes, neg_nodes, neighbors, nbr_eidx, emb);
    aff_kernel<<<2 * BATCH, 256, 0, stream>>>(emb, aff_w1, aff_b1, aff_w2, aff_b2, out);
}

// Round 2
// 3147.930 us; speedup vs baseline: 2.0770x; 2.0770x over previous
//
#include <hip/hip_runtime.h>
#include <math.h>

// ---------------- problem constants ----------------
#define N_NODES 100000
#define BATCH   2000
#define KNBR    20
#define DF      172      // D
#define MSGD    688      // 2D + D + T
#define M3      6000     // 3*B query rows
#define DH      86       // head dim (2 heads)
#define KIN_D   516      // D + D + T  (k_in width)

// GRU GEMM (swapped operands): D(JP x N_NODES) = W'(JP x KA) * X^T
//  W' rows reordered gate-major: j = 4*d + g, g in {r, z, n_i, n_h}
#define KA      864      // padded K (860 -> 864, multiple of 32)
#define JP      768      // padded W' rows: 4*192 (d padded 172->192)
#define KREAL   860
#define NTILES_N ((N_NODES + 127) / 128)   // 782

typedef __bf16 bf16x8 __attribute__((ext_vector_type(8)));
typedef float  f32x4  __attribute__((ext_vector_type(4)));

// ---------------- ws layout (floats) ----------------
#define WPB_OFF 0
#define WPB_SZ  ((JP * KA) / 2)          // bf16 array occupying float slots
#define BP4_OFF (WPB_OFF + WPB_SZ)
#define BP4_SZ  JP
#define MU_OFF  (BP4_OFF + BP4_SZ)
#define MU_SZ   (N_NODES * DF)
#define EMB_OFF (MU_OFF + MU_SZ)

__device__ __forceinline__ float sigmoidf_(float x) { return 1.0f / (1.0f + expf(-x)); }

// ============================================================
// Kernel 0: build gate-major bf16 W' (JP x KA) and fused bias bp4 (JP)
//  j = 4*d + g:
//   g=0 (r):  [w_ih[d]      | w_hh[d]],       bias b_ih[d]+b_hh[d]
//   g=1 (z):  [w_ih[d+172]  | w_hh[d+172]],   bias sum
//   g=2 (ni): [w_ih[d+344]  | 0],             bias b_ih[d+344]
//   g=3 (nh): [0            | w_hh[d+344]],   bias b_hh[d+344]
// ============================================================
__global__ __launch_bounds__(256) void prep_kernel(
    const float* __restrict__ w_ih, const float* __restrict__ w_hh,
    const float* __restrict__ b_ih, const float* __restrict__ b_hh,
    __bf16* __restrict__ wpb, float* __restrict__ bp4)
{
    int idx = blockIdx.x * 256 + threadIdx.x;
    if (idx < JP * KA) {
        int j = idx / KA, k = idx - j * KA;
        int d = j >> 2, g = j & 3;
        float v = 0.f;
        if (d < DF) {
            if (g == 0) {
                if (k < MSGD) v = w_ih[d * MSGD + k];
                else if (k < KREAL) v = w_hh[d * DF + (k - MSGD)];
            } else if (g == 1) {
                if (k < MSGD) v = w_ih[(d + DF) * MSGD + k];
                else if (k < KREAL) v = w_hh[(d + DF) * DF + (k - MSGD)];
            } else if (g == 2) {
                if (k < MSGD) v = w_ih[(d + 2 * DF) * MSGD + k];
            } else {
                if (k >= MSGD && k < KREAL) v = w_hh[(d + 2 * DF) * DF + (k - MSGD)];
            }
        }
        wpb[idx] = (__bf16)v;
    }
    if (idx < JP) {
        int d = idx >> 2, g = idx & 3;
        float b = 0.f;
        if (d < DF) {
            if (g == 0) b = b_ih[d] + b_hh[d];
            else if (g == 1) b = b_ih[d + DF] + b_hh[d + DF];
            else if (g == 2) b = b_ih[d + 2 * DF];
            else            b = b_hh[d + 2 * DF];
        }
        bp4[idx] = b;
    }
}

// ============================================================
// Kernel 1: MFMA GRU GEMM + lane-local fused epilogue
//  128x128 tile, BK=32, 4 waves (each 64x64 quadrant, 4x4 frags of 16x16x32).
//  M-side = W' rows (gate-major) -> gates land in acc regs 0..3.
//  N-side = node rows; X = [messages|memory|0] converted fp32->bf16 on the fly.
// ============================================================
__global__ __launch_bounds__(256) void gru_mfma_kernel(
    const float* __restrict__ messages, const float* __restrict__ memory,
    const __bf16* __restrict__ wpb, const float* __restrict__ bp4,
    float* __restrict__ mem_upd)
{
    __shared__ __align__(16) __bf16 Ws[128][32];   // W' tile (M x K)
    __shared__ __align__(16) __bf16 Xs[128][32];   // X tile  (N x K)

    const int t    = threadIdx.x;
    const int w    = t >> 6, lane = t & 63;
    const int lo   = lane & 15, hi = lane >> 4;
    const int wm   = w >> 1, wn = w & 1;

    const int bx     = blockIdx.x;
    const int n_tile = bx / 6;                 // consecutive bx share the X panel -> L2 reuse
    const int m_tile = bx - n_tile * 6;
    const int n0     = n_tile * 128;
    const int j0     = m_tile * 128;

    // staging thread mapping: thread t -> tile row t>>1, half t&1 (16 elems)
    const int xrow  = t >> 1, xhalf = t & 1;
    const int nr    = min(n0 + xrow, N_NODES - 1);
    const float* mrow = messages + (size_t)nr * MSGD;
    const float* hrow = memory   + (size_t)nr * DF;
    const __bf16* wrow = wpb + (size_t)(j0 + xrow) * KA;

    f32x4 acc[4][4];
#pragma unroll
    for (int mi = 0; mi < 4; ++mi)
#pragma unroll
        for (int ni = 0; ni < 4; ++ni)
            acc[mi][ni] = (f32x4){0.f, 0.f, 0.f, 0.f};

    for (int k0 = 0; k0 < KA; k0 += 32) {
        // ---- stage W' tile (bf16 direct) ----
        bf16x8 w0 = *(const bf16x8*)(wrow + k0 + xhalf * 16);
        bf16x8 w1 = *(const bf16x8*)(wrow + k0 + xhalf * 16 + 8);
        // ---- stage X tile (fp32 -> bf16) ----
        float fl[16];
#pragma unroll
        for (int c = 0; c < 4; ++c) {
            const int kb = k0 + xhalf * 16 + c * 4;
            float4 v;
            if (kb < MSGD)       v = *(const float4*)(mrow + kb);
            else if (kb < KREAL) v = *(const float4*)(hrow + (kb - MSGD));
            else                 v = make_float4(0.f, 0.f, 0.f, 0.f);
            fl[c * 4 + 0] = v.x; fl[c * 4 + 1] = v.y;
            fl[c * 4 + 2] = v.z; fl[c * 4 + 3] = v.w;
        }
        bf16x8 x0, x1;
#pragma unroll
        for (int jj = 0; jj < 8; ++jj) {
            x0[jj] = (__bf16)fl[jj];
            x1[jj] = (__bf16)fl[8 + jj];
        }
        *(bf16x8*)&Ws[xrow][xhalf * 16]     = w0;
        *(bf16x8*)&Ws[xrow][xhalf * 16 + 8] = w1;
        *(bf16x8*)&Xs[xrow][xhalf * 16]     = x0;
        *(bf16x8*)&Xs[xrow][xhalf * 16 + 8] = x1;
        __syncthreads();

        // ---- fragments + 16 MFMA ----
        bf16x8 af[4], bx_[4];
#pragma unroll
        for (int i = 0; i < 4; ++i) {
            af[i]  = *(const bf16x8*)&Ws[wm * 64 + i * 16 + lo][hi * 8];
            bx_[i] = *(const bf16x8*)&Xs[wn * 64 + i * 16 + lo][hi * 8];
        }
#pragma unroll
        for (int mi = 0; mi < 4; ++mi)
#pragma unroll
            for (int ni = 0; ni < 4; ++ni)
                acc[mi][ni] = __builtin_amdgcn_mfma_f32_16x16x32_bf16(
                    af[mi], bx_[ni], acc[mi][ni], 0, 0, 0);
        __syncthreads();
    }

    // ---- fused GRU epilogue (lane-local: gates are regs 0..3) ----
    const int dbase = m_tile * 32 + wm * 16;
#pragma unroll
    for (int mi = 0; mi < 4; ++mi) {
        const int d = dbase + mi * 4 + hi;
        if (d >= DF) continue;
        const float4 b4 = *(const float4*)&bp4[4 * d];
#pragma unroll
        for (int ni = 0; ni < 4; ++ni) {
            const int n = n0 + wn * 64 + ni * 16 + lo;
            if (n >= N_NODES) continue;
            float sr  = acc[mi][ni][0] + b4.x;
            float sz  = acc[mi][ni][1] + b4.y;
            float gin = acc[mi][ni][2] + b4.z;
            float ghn = acc[mi][ni][3] + b4.w;
            float mem = memory[(size_t)n * DF + d];
            float rg  = sigmoidf_(sr);
            float zg  = sigmoidf_(sz);
            float nt  = tanhf(fmaf(rg, ghn, gin));
            mem_upd[(size_t)n * DF + d] = fmaf(zg, mem - nt, nt);
        }
    }
}

// ============================================================
// Kernel 2: per-query attention + merge MLP (one block per row, 6000 rows)
// ============================================================
__global__ __launch_bounds__(256) void attn_kernel(
    const float* __restrict__ mem_upd, const float* __restrict__ edge_features,
    const float* __restrict__ edge_times, const float* __restrict__ neighbor_times,
    const float* __restrict__ time_w, const float* __restrict__ time_b,
    const float* __restrict__ w_q, const float* __restrict__ w_k,
    const float* __restrict__ w_v, const float* __restrict__ w_o,
    const float* __restrict__ merge_w1, const float* __restrict__ merge_b1,
    const float* __restrict__ merge_w2, const float* __restrict__ merge_b2,
    const int* __restrict__ src_nodes, const int* __restrict__ dst_nodes,
    const int* __restrict__ neg_nodes, const int* __restrict__ neighbors,
    const int* __restrict__ nbr_eidx, float* __restrict__ emb)
{
    __shared__ __align__(16) float kin[KNBR][KIN_D];  // 41.3 KB
    __shared__ float kkl[KNBR][DF];                   // 13.8 KB
    __shared__ float sf[DF];
    __shared__ __align__(16) float qin[344];
    __shared__ float qv[DF];
    __shared__ float ctxl[DF];
    __shared__ float scl[2][KNBR];
    __shared__ float attnl[2][KNBR];
    __shared__ __align__(16) float catl[344];
    __shared__ float h1l[DF];
    __shared__ int   nbrs[KNBR];
    __shared__ int   eidxs[KNBR];
    __shared__ float dts[KNBR];

    const int i = blockIdx.x;
    const int t = threadIdx.x;

    int node;
    if (i < BATCH)          node = src_nodes[i];
    else if (i < 2 * BATCH) node = dst_nodes[i - BATCH];
    else                    node = neg_nodes[i - 2 * BATCH];
    const float tsv = edge_times[i % BATCH];

    if (t < KNBR) {
        nbrs[t]  = neighbors[i * KNBR + t];
        eidxs[t] = nbr_eidx[i * KNBR + t];
        dts[t]   = tsv - neighbor_times[i * KNBR + t];
    }
    if (t < DF) {
        float v = mem_upd[node * DF + t];
        sf[t] = v;
        qin[t] = v;
        qin[DF + t] = cosf(time_b[t]);   // time_enc(0)
    }
    __syncthreads();

    // q = q_in @ w_q^T
    if (t < DF) {
        float s = 0.f;
#pragma unroll 4
        for (int j = 0; j < 344; ++j) s = fmaf(qin[j], w_q[t * 344 + j], s);
        qv[t] = s;
    }
    // fill k_in (20 x 516): [nbr_feat | e_feat | time_enc(dt)]
    for (int idx = t; idx < KNBR * KIN_D; idx += 256) {
        int kn = idx / KIN_D, c = idx - kn * KIN_D;
        float v;
        if (c < DF)       v = mem_upd[nbrs[kn] * DF + c];
        else if (c < 344) v = edge_features[eidxs[kn] * DF + (c - DF)];
        else { int j = c - 344; v = cosf(fmaf(dts[kn], time_w[j], time_b[j])); }
        kin[kn][c] = v;
    }
    __syncthreads();

    // K,V projections: thread d owns output dim d for all 20 neighbors.
    float av[KNBR];
    if (t < DF) {
        float ak[KNBR];
#pragma unroll
        for (int kn = 0; kn < KNBR; ++kn) { ak[kn] = 0.f; av[kn] = 0.f; }
        const float4* wkp = reinterpret_cast<const float4*>(&w_k[t * KIN_D]);
        const float4* wvp = reinterpret_cast<const float4*>(&w_v[t * KIN_D]);
        for (int c4 = 0; c4 < KIN_D / 4; ++c4) {
            float4 wk = wkp[c4];
            float4 wv = wvp[c4];
#pragma unroll
            for (int kn = 0; kn < KNBR; ++kn) {
                float4 kv = *reinterpret_cast<const float4*>(&kin[kn][c4 * 4]);
                ak[kn] = fmaf(wk.x, kv.x, ak[kn]); ak[kn] = fmaf(wk.y, kv.y, ak[kn]);
                ak[kn] = fmaf(wk.z, kv.z, ak[kn]); ak[kn] = fmaf(wk.w, kv.w, ak[kn]);
                av[kn] = fmaf(wv.x, kv.x, av[kn]); av[kn] = fmaf(wv.y, kv.y, av[kn]);
                av[kn] = fmaf(wv.z, kv.z, av[kn]); av[kn] = fmaf(wv.w, kv.w, av[kn]);
            }
        }
#pragma unroll
        for (int kn = 0; kn < KNBR; ++kn) kkl[kn][t] = ak[kn];
    }
    __syncthreads();

    // scores (2 heads x 20 nbrs) + mask
    if (t < 2 * KNBR) {
        int h = t / KNBR, kn = t - h * KNBR;
        float s = 0.f;
#pragma unroll 2
        for (int j = 0; j < DH; ++j) s = fmaf(qv[h * DH + j], kkl[kn][h * DH + j], s);
        s /= sqrtf((float)DH);
        scl[h][kn] = (nbrs[kn] > 0) ? s : -1e9f;
    }
    __syncthreads();
    if (t < 2) {
        float m = -INFINITY;
        for (int kn = 0; kn < KNBR; ++kn) m = fmaxf(m, scl[t][kn]);
        float se = 0.f;
        for (int kn = 0; kn < KNBR; ++kn) se += expf(scl[t][kn] - m);
        float inv = 1.f / se;
        for (int kn = 0; kn < KNBR; ++kn) attnl[t][kn] = expf(scl[t][kn] - m) * inv;
    }
    __syncthreads();
    // ctx (V is still in registers per-thread)
    if (t < DF) {
        int h = t / DH;
        float cx = 0.f;
#pragma unroll
        for (int kn = 0; kn < KNBR; ++kn) cx = fmaf(attnl[h][kn], av[kn], cx);
        ctxl[t] = cx;
    }
    __syncthreads();
    // w_o projection, build concat [ctx_o | src_feat]
    if (t < DF) {
        float s = 0.f;
#pragma unroll 4
        for (int j = 0; j < DF; ++j) s = fmaf(ctxl[j], w_o[t * DF + j], s);
        catl[t] = s;
        catl[DF + t] = sf[t];
    }
    __syncthreads();
    if (t < DF) {
        float s = merge_b1[t];
#pragma unroll 4
        for (int j = 0; j < 344; ++j) s = fmaf(catl[j], merge_w1[t * 344 + j], s);
        h1l[t] = fmaxf(s, 0.f);
    }
    __syncthreads();
    if (t < DF) {
        float s = merge_b2[t];
#pragma unroll 4
        for (int j = 0; j < DF; ++j) s = fmaf(h1l[j], merge_w2[t * DF + j], s);
        emb[i * DF + t] = s;
    }
}

// ============================================================
// Kernel 3: affinity MLP -> sigmoid prob (4000 pairs)
// ============================================================
__global__ __launch_bounds__(256) void aff_kernel(
    const float* __restrict__ emb,
    const float* __restrict__ aff_w1, const float* __restrict__ aff_b1,
    const float* __restrict__ aff_w2, const float* __restrict__ aff_b2,
    float* __restrict__ out)
{
    __shared__ __align__(16) float pair[344];
    __shared__ float ahl[DF];
    __shared__ float red[4];
    const int j = blockIdx.x;
    const int t = threadIdx.x;
    const int s_idx = (j < BATCH) ? j : (j - BATCH);
    const int d_idx = (j < BATCH) ? (BATCH + j) : (2 * BATCH + (j - BATCH));
    if (t < DF) {
        pair[t]      = emb[s_idx * DF + t];
        pair[DF + t] = emb[d_idx * DF + t];
    }
    __syncthreads();
    if (t < DF) {
        float s = aff_b1[t];
#pragma unroll 4
        for (int c = 0; c < 344; ++c) s = fmaf(pair[c], aff_w1[t * 344 + c], s);
        ahl[t] = fmaxf(s, 0.f);
    }
    __syncthreads();
    float p = 0.f;
    if (t < DF) p = ahl[t] * aff_w2[t];
#pragma unroll
    for (int off = 32; off > 0; off >>= 1) p += __shfl_down(p, off, 64);
    if ((t & 63) == 0) red[t >> 6] = p;
    __syncthreads();
    if (t == 0) {
        float s = red[0] + red[1] + red[2] + red[3] + aff_b2[0];
        out[j] = 1.f / (1.f + expf(-s));
    }
}

// ============================================================
extern "C" void kernel_launch(void* const* d_in, const int* in_sizes, int n_in,
                              void* d_out, int out_size, void* d_ws, size_t ws_size,
                              hipStream_t stream)
{
    (void)in_sizes; (void)n_in; (void)out_size; (void)ws_size;
    const float* memory         = (const float*)d_in[0];
    const float* messages       = (const float*)d_in[1];
    const float* edge_features  = (const float*)d_in[2];
    const float* edge_times     = (const float*)d_in[3];
    const float* neighbor_times = (const float*)d_in[4];
    const float* time_w         = (const float*)d_in[5];
    const float* time_b         = (const float*)d_in[6];
    const float* gru_w_ih       = (const float*)d_in[7];
    const float* gru_w_hh       = (const float*)d_in[8];
    const float* gru_b_ih       = (const float*)d_in[9];
    const float* gru_b_hh       = (const float*)d_in[10];
    const float* w_q            = (const float*)d_in[11];
    const float* w_k            = (const float*)d_in[12];
    const float* w_v            = (const float*)d_in[13];
    const float* w_o            = (const float*)d_in[14];
    const float* merge_w1       = (const float*)d_in[15];
    const float* merge_b1       = (const float*)d_in[16];
    const float* merge_w2       = (const float*)d_in[17];
    const float* merge_b2       = (const float*)d_in[18];
    const float* aff_w1         = (const float*)d_in[19];
    const float* aff_b1         = (const float*)d_in[20];
    const float* aff_w2         = (const float*)d_in[21];
    const float* aff_b2         = (const float*)d_in[22];
    const int* src_nodes        = (const int*)d_in[23];
    const int* dst_nodes        = (const int*)d_in[24];
    const int* neg_nodes        = (const int*)d_in[25];
    const int* neighbors        = (const int*)d_in[26];
    const int* nbr_eidx         = (const int*)d_in[27];

    float* ws       = (float*)d_ws;
    __bf16* wpb     = (__bf16*)(ws + WPB_OFF);
    float* bp4      = ws + BP4_OFF;
    float* mem_upd  = ws + MU_OFF;
    float* emb      = ws + EMB_OFF;
    float* out      = (float*)d_out;

    prep_kernel<<<(JP * KA + 255) / 256, 256, 0, stream>>>(
        gru_w_ih, gru_w_hh, gru_b_ih, gru_b_hh, wpb, bp4);
    gru_mfma_kernel<<<NTILES_N * 6, 256, 0, stream>>>(
        messages, memory, wpb, bp4, mem_upd);
    attn_kernel<<<M3, 256, 0, stream>>>(mem_upd, edge_features, edge_times,
        neighbor_times, time_w, time_b, w_q, w_k, w_v, w_o,
        merge_w1, merge_b1, merge_w2, merge_b2,
        src_nodes, dst_nodes, neg_nodes, neighbors, nbr_eidx, emb);
    aff_kernel<<<2 * BATCH, 256, 0, stream>>>(emb, aff_w1, aff_b1, aff_w2, aff_b2, out);
}

// Round 3
// 1824.636 us; speedup vs baseline: 3.5833x; 1.7252x over previous
//
#include <hip/hip_runtime.h>
#include <math.h>

// ---------------- problem constants ----------------
#define N_NODES 100000
#define BATCH   2000
#define KNBR    20
#define DF      172      // D
#define MSGD    688      // 2D + D + T
#define M3      6000     // 3*B query rows
#define DH      86       // head dim (2 heads)
#define KIN_D   516      // D + D + T  (k_in width)

// GRU GEMM (swapped operands): D(JP x N_NODES) = W'(JP x KA) * X^T
#define KA      864
#define JP      768
#define KREAL   860
#define NTILES_N ((N_NODES + 127) / 128)   // 782

// KV GEMM: D(JKV x NKV) = Wkv'(JKV x KP_KV) * kin^T
#define NKV     120000   // 6000 * 20
#define KP_KV   544      // 516 padded to 17*32
#define JKV     384      // [K: 0..171 | pad | V: 192..363 | pad]
#define KVS     352      // kv row stride in bf16 elems: [k 0..171|pad 4|v 0..171|pad 4]
#define NKV_TILES ((NKV + 127) / 128)      // 938

typedef __bf16 bf16x8 __attribute__((ext_vector_type(8)));
typedef __bf16 bf16x4 __attribute__((ext_vector_type(4)));
typedef float  f32x4  __attribute__((ext_vector_type(4)));

// ---------------- ws layout (floats) ----------------
#define WPB_OFF 0
#define WPB_SZ  ((JP * KA) / 2)              // 331776
#define BP4_OFF (WPB_OFF + WPB_SZ)
#define BP4_SZ  JP
#define WKV_OFF (BP4_OFF + BP4_SZ)
#define WKV_SZ  ((JKV * KP_KV) / 2)          // 104448
#define MU_OFF  (WKV_OFF + WKV_SZ)
#define MU_SZ   (N_NODES * DF)
#define KV_OFF  (MU_OFF + MU_SZ)
#define KV_SZ   ((NKV * KVS) / 2)            // 21.12M floats
#define EMB_OFF (KV_OFF + KV_SZ)

__device__ __forceinline__ float sigmoidf_(float x) { return 1.0f / (1.0f + expf(-x)); }

// ============================================================
// Kernel 0a: gate-major bf16 GRU weight W' (JP x KA) + fused bias
// ============================================================
__global__ __launch_bounds__(256) void prep_kernel(
    const float* __restrict__ w_ih, const float* __restrict__ w_hh,
    const float* __restrict__ b_ih, const float* __restrict__ b_hh,
    __bf16* __restrict__ wpb, float* __restrict__ bp4)
{
    int idx = blockIdx.x * 256 + threadIdx.x;
    if (idx < JP * KA) {
        int j = idx / KA, k = idx - j * KA;
        int d = j >> 2, g = j & 3;
        float v = 0.f;
        if (d < DF) {
            if (g == 0) {
                if (k < MSGD) v = w_ih[d * MSGD + k];
                else if (k < KREAL) v = w_hh[d * DF + (k - MSGD)];
            } else if (g == 1) {
                if (k < MSGD) v = w_ih[(d + DF) * MSGD + k];
                else if (k < KREAL) v = w_hh[(d + DF) * DF + (k - MSGD)];
            } else if (g == 2) {
                if (k < MSGD) v = w_ih[(d + 2 * DF) * MSGD + k];
            } else {
                if (k >= MSGD && k < KREAL) v = w_hh[(d + 2 * DF) * DF + (k - MSGD)];
            }
        }
        wpb[idx] = (__bf16)v;
    }
    if (idx < JP) {
        int d = idx >> 2, g = idx & 3;
        float b = 0.f;
        if (d < DF) {
            if (g == 0) b = b_ih[d] + b_hh[d];
            else if (g == 1) b = b_ih[d + DF] + b_hh[d + DF];
            else if (g == 2) b = b_ih[d + 2 * DF];
            else            b = b_hh[d + 2 * DF];
        }
        bp4[idx] = b;
    }
}

// ============================================================
// Kernel 0b: combined bf16 KV weight (JKV x KP_KV)
//  j<172: w_k[j]; 192<=j<364: w_v[j-192]; else 0. k>=516 -> 0.
// ============================================================
__global__ __launch_bounds__(256) void prep_kv_kernel(
    const float* __restrict__ w_k, const float* __restrict__ w_v,
    __bf16* __restrict__ wkvb)
{
    int idx = blockIdx.x * 256 + threadIdx.x;
    if (idx < JKV * KP_KV) {
        int j = idx / KP_KV, k = idx - j * KP_KV;
        float v = 0.f;
        if (k < KIN_D) {
            if (j < DF) v = w_k[j * KIN_D + k];
            else if (j >= 192 && j < 192 + DF) v = w_v[(j - 192) * KIN_D + k];
        }
        wkvb[idx] = (__bf16)v;
    }
}

// ============================================================
// Kernel 1: MFMA GRU GEMM + lane-local fused epilogue (unchanged from R2)
// ============================================================
__global__ __launch_bounds__(256) void gru_mfma_kernel(
    const float* __restrict__ messages, const float* __restrict__ memory,
    const __bf16* __restrict__ wpb, const float* __restrict__ bp4,
    float* __restrict__ mem_upd)
{
    __shared__ __align__(16) __bf16 Ws[128][32];
    __shared__ __align__(16) __bf16 Xs[128][32];

    const int t    = threadIdx.x;
    const int w    = t >> 6, lane = t & 63;
    const int lo   = lane & 15, hi = lane >> 4;
    const int wm   = w >> 1, wn = w & 1;

    const int bx     = blockIdx.x;
    const int n_tile = bx / 6;
    const int m_tile = bx - n_tile * 6;
    const int n0     = n_tile * 128;
    const int j0     = m_tile * 128;

    const int xrow  = t >> 1, xhalf = t & 1;
    const int nr    = min(n0 + xrow, N_NODES - 1);
    const float* mrow = messages + (size_t)nr * MSGD;
    const float* hrow = memory   + (size_t)nr * DF;
    const __bf16* wrow = wpb + (size_t)(j0 + xrow) * KA;

    f32x4 acc[4][4];
#pragma unroll
    for (int mi = 0; mi < 4; ++mi)
#pragma unroll
        for (int ni = 0; ni < 4; ++ni)
            acc[mi][ni] = (f32x4){0.f, 0.f, 0.f, 0.f};

    for (int k0 = 0; k0 < KA; k0 += 32) {
        bf16x8 w0 = *(const bf16x8*)(wrow + k0 + xhalf * 16);
        bf16x8 w1 = *(const bf16x8*)(wrow + k0 + xhalf * 16 + 8);
        float fl[16];
#pragma unroll
        for (int c = 0; c < 4; ++c) {
            const int kb = k0 + xhalf * 16 + c * 4;
            float4 v;
            if (kb < MSGD)       v = *(const float4*)(mrow + kb);
            else if (kb < KREAL) v = *(const float4*)(hrow + (kb - MSGD));
            else                 v = make_float4(0.f, 0.f, 0.f, 0.f);
            fl[c * 4 + 0] = v.x; fl[c * 4 + 1] = v.y;
            fl[c * 4 + 2] = v.z; fl[c * 4 + 3] = v.w;
        }
        bf16x8 x0, x1;
#pragma unroll
        for (int jj = 0; jj < 8; ++jj) {
            x0[jj] = (__bf16)fl[jj];
            x1[jj] = (__bf16)fl[8 + jj];
        }
        *(bf16x8*)&Ws[xrow][xhalf * 16]     = w0;
        *(bf16x8*)&Ws[xrow][xhalf * 16 + 8] = w1;
        *(bf16x8*)&Xs[xrow][xhalf * 16]     = x0;
        *(bf16x8*)&Xs[xrow][xhalf * 16 + 8] = x1;
        __syncthreads();

        bf16x8 af[4], bx_[4];
#pragma unroll
        for (int i = 0; i < 4; ++i) {
            af[i]  = *(const bf16x8*)&Ws[wm * 64 + i * 16 + lo][hi * 8];
            bx_[i] = *(const bf16x8*)&Xs[wn * 64 + i * 16 + lo][hi * 8];
        }
#pragma unroll
        for (int mi = 0; mi < 4; ++mi)
#pragma unroll
            for (int ni = 0; ni < 4; ++ni)
                acc[mi][ni] = __builtin_amdgcn_mfma_f32_16x16x32_bf16(
                    af[mi], bx_[ni], acc[mi][ni], 0, 0, 0);
        __syncthreads();
    }

    const int dbase = m_tile * 32 + wm * 16;
#pragma unroll
    for (int mi = 0; mi < 4; ++mi) {
        const int d = dbase + mi * 4 + hi;
        if (d >= DF) continue;
        const float4 b4 = *(const float4*)&bp4[4 * d];
#pragma unroll
        for (int ni = 0; ni < 4; ++ni) {
            const int n = n0 + wn * 64 + ni * 16 + lo;
            if (n >= N_NODES) continue;
            float sr  = acc[mi][ni][0] + b4.x;
            float sz  = acc[mi][ni][1] + b4.y;
            float gin = acc[mi][ni][2] + b4.z;
            float ghn = acc[mi][ni][3] + b4.w;
            float mem = memory[(size_t)n * DF + d];
            float rg  = sigmoidf_(sr);
            float zg  = sigmoidf_(sz);
            float nt  = tanhf(fmaf(rg, ghn, gin));
            mem_upd[(size_t)n * DF + d] = fmaf(zg, mem - nt, nt);
        }
    }
}

// ============================================================
// Kernel 2: batched K/V projection GEMM with on-the-fly kin build
//  D(JKV x NKV) = Wkv' x kin^T ; kin row n: i=n/20, kn=n%20
//  [mem_upd[nbr] | edge_features[eidx] | cos(dt*w+b) | 0pad]
//  Output kv bf16: row n = [k(172) | pad | v(172) | pad], stride 352
// ============================================================
__global__ __launch_bounds__(256) void kv_gemm_kernel(
    const float* __restrict__ mem_upd, const float* __restrict__ edge_features,
    const float* __restrict__ edge_times, const float* __restrict__ neighbor_times,
    const float* __restrict__ time_w, const float* __restrict__ time_b,
    const int* __restrict__ neighbors, const int* __restrict__ nbr_eidx,
    const __bf16* __restrict__ wkvb, __bf16* __restrict__ kv)
{
    __shared__ __align__(16) __bf16 Ws[128][32];
    __shared__ __align__(16) __bf16 Xs[128][32];

    const int t    = threadIdx.x;
    const int w    = t >> 6, lane = t & 63;
    const int lo   = lane & 15, hi = lane >> 4;
    const int wm   = w >> 1, wn = w & 1;

    const int bx     = blockIdx.x;
    const int n_tile = bx / 3;
    const int m_tile = bx - n_tile * 3;
    const int n0     = n_tile * 128;
    const int j0     = m_tile * 128;

    const int xrow  = t >> 1, xhalf = t & 1;
    const int nr    = min(n0 + xrow, NKV - 1);
    const int nbr   = neighbors[nr];
    const int eidx  = nbr_eidx[nr];
    const float dt  = edge_times[(nr / KNBR) % BATCH] - neighbor_times[nr];
    const float* mrow = mem_upd       + (size_t)nbr  * DF;
    const float* erow = edge_features + (size_t)eidx * DF;
    const __bf16* wrow = wkvb + (size_t)(j0 + xrow) * KP_KV;

    f32x4 acc[4][4];
#pragma unroll
    for (int mi = 0; mi < 4; ++mi)
#pragma unroll
        for (int ni = 0; ni < 4; ++ni)
            acc[mi][ni] = (f32x4){0.f, 0.f, 0.f, 0.f};

    for (int k0 = 0; k0 < KP_KV; k0 += 32) {
        bf16x8 w0 = *(const bf16x8*)(wrow + k0 + xhalf * 16);
        bf16x8 w1 = *(const bf16x8*)(wrow + k0 + xhalf * 16 + 8);
        float fl[16];
#pragma unroll
        for (int c = 0; c < 4; ++c) {
            const int kb = k0 + xhalf * 16 + c * 4;   // 4-aligned; segments are 4-aligned
            float4 v;
            if (kb < DF) {
                v = *(const float4*)(mrow + kb);
            } else if (kb < 2 * DF) {
                v = *(const float4*)(erow + (kb - DF));
            } else if (kb < KIN_D) {
                const float4 tw = *(const float4*)(time_w + (kb - 2 * DF));
                const float4 tb = *(const float4*)(time_b + (kb - 2 * DF));
                v.x = cosf(fmaf(dt, tw.x, tb.x));
                v.y = cosf(fmaf(dt, tw.y, tb.y));
                v.z = cosf(fmaf(dt, tw.z, tb.z));
                v.w = cosf(fmaf(dt, tw.w, tb.w));
            } else {
                v = make_float4(0.f, 0.f, 0.f, 0.f);
            }
            fl[c * 4 + 0] = v.x; fl[c * 4 + 1] = v.y;
            fl[c * 4 + 2] = v.z; fl[c * 4 + 3] = v.w;
        }
        bf16x8 x0, x1;
#pragma unroll
        for (int jj = 0; jj < 8; ++jj) {
            x0[jj] = (__bf16)fl[jj];
            x1[jj] = (__bf16)fl[8 + jj];
        }
        *(bf16x8*)&Ws[xrow][xhalf * 16]     = w0;
        *(bf16x8*)&Ws[xrow][xhalf * 16 + 8] = w1;
        *(bf16x8*)&Xs[xrow][xhalf * 16]     = x0;
        *(bf16x8*)&Xs[xrow][xhalf * 16 + 8] = x1;
        __syncthreads();

        bf16x8 af[4], bx_[4];
#pragma unroll
        for (int i = 0; i < 4; ++i) {
            af[i]  = *(const bf16x8*)&Ws[wm * 64 + i * 16 + lo][hi * 8];
            bx_[i] = *(const bf16x8*)&Xs[wn * 64 + i * 16 + lo][hi * 8];
        }
#pragma unroll
        for (int mi = 0; mi < 4; ++mi)
#pragma unroll
            for (int ni = 0; ni < 4; ++ni)
                acc[mi][ni] = __builtin_amdgcn_mfma_f32_16x16x32_bf16(
                    af[mi], bx_[ni], acc[mi][ni], 0, 0, 0);
        __syncthreads();
    }

    // epilogue: j regs r=0..3 consecutive -> one 8B bf16x4 store per frag
#pragma unroll
    for (int mi = 0; mi < 4; ++mi) {
        const int jb = j0 + wm * 64 + mi * 16 + hi * 4;
        int off;
        if (jb + 3 < DF)                 off = jb;        // K region
        else if (jb >= 192 && jb < 361)  off = jb - 16;   // V region -> 176 + (jb-192)
        else continue;
#pragma unroll
        for (int ni = 0; ni < 4; ++ni) {
            const int n = n0 + wn * 64 + ni * 16 + lo;
            if (n >= NKV) continue;
            bf16x4 o;
            o[0] = (__bf16)acc[mi][ni][0];
            o[1] = (__bf16)acc[mi][ni][1];
            o[2] = (__bf16)acc[mi][ni][2];
            o[3] = (__bf16)acc[mi][ni][3];
            *(bf16x4*)(kv + (size_t)n * KVS + off) = o;
        }
    }
}

// ============================================================
// Kernel 3: per-query attention (reads precomputed KV) + merge MLP
// ============================================================
__global__ __launch_bounds__(256) void attn_lite_kernel(
    const float* __restrict__ mem_upd, const __bf16* __restrict__ kv,
    const float* __restrict__ time_b,
    const float* __restrict__ w_q, const float* __restrict__ w_o,
    const float* __restrict__ merge_w1, const float* __restrict__ merge_b1,
    const float* __restrict__ merge_w2, const float* __restrict__ merge_b2,
    const int* __restrict__ src_nodes, const int* __restrict__ dst_nodes,
    const int* __restrict__ neg_nodes, const int* __restrict__ neighbors,
    float* __restrict__ emb)
{
    __shared__ __align__(16) __bf16 kvs[KNBR][KVS];   // 14.1 KB
    __shared__ __align__(16) float qin[344];
    __shared__ __align__(16) float qv[DF];
    __shared__ __align__(16) float ctxl[DF];
    __shared__ __align__(16) float catl[344];
    __shared__ __align__(16) float h1l[DF];
    __shared__ float sf[DF];
    __shared__ float scl[2][KNBR];
    __shared__ float attnl[2][KNBR];
    __shared__ int   nbrs[KNBR];

    const int i = blockIdx.x;
    const int t = threadIdx.x;

    int node;
    if (i < BATCH)          node = src_nodes[i];
    else if (i < 2 * BATCH) node = dst_nodes[i - BATCH];
    else                    node = neg_nodes[i - 2 * BATCH];

    if (t < KNBR) nbrs[t] = neighbors[i * KNBR + t];
    if (t < DF) {
        float v = mem_upd[(size_t)node * DF + t];
        sf[t] = v;
        qin[t] = v;
        qin[DF + t] = cosf(time_b[t]);   // time_enc(0)
    }
    // stage the 20x352 bf16 KV slab (contiguous: rows i*20..i*20+19)
    {
        const uint4* src = (const uint4*)(kv + (size_t)i * KNBR * KVS);
        uint4* dst = (uint4*)&kvs[0][0];
        for (int idx = t; idx < KNBR * KVS / 8; idx += 256) dst[idx] = src[idx];
    }
    __syncthreads();

    // q projection (float4 weight loads)
    if (t < DF) {
        const float4* wq4 = (const float4*)(w_q + (size_t)t * 344);
        const float4* qi4 = (const float4*)qin;
        float s = 0.f;
#pragma unroll 4
        for (int j = 0; j < 86; ++j) {
            float4 a = qi4[j], b = wq4[j];
            s = fmaf(a.x, b.x, s); s = fmaf(a.y, b.y, s);
            s = fmaf(a.z, b.z, s); s = fmaf(a.w, b.w, s);
        }
        qv[t] = s;
    }
    __syncthreads();

    // scores (2 heads x 20 nbrs) + mask
    if (t < 2 * KNBR) {
        int h = t / KNBR, kn = t - h * KNBR;
        float s = 0.f;
#pragma unroll 2
        for (int j = 0; j < DH; ++j)
            s = fmaf(qv[h * DH + j], (float)kvs[kn][h * DH + j], s);
        s /= sqrtf((float)DH);
        scl[h][kn] = (nbrs[kn] > 0) ? s : -1e9f;
    }
    __syncthreads();
    if (t < 2) {
        float m = -INFINITY;
        for (int kn = 0; kn < KNBR; ++kn) m = fmaxf(m, scl[t][kn]);
        float se = 0.f;
        for (int kn = 0; kn < KNBR; ++kn) se += expf(scl[t][kn] - m);
        float inv = 1.f / se;
        for (int kn = 0; kn < KNBR; ++kn) attnl[t][kn] = expf(scl[t][kn] - m) * inv;
    }
    __syncthreads();
    // ctx
    if (t < DF) {
        int h = t / DH;
        float cx = 0.f;
#pragma unroll
        for (int kn = 0; kn < KNBR; ++kn)
            cx = fmaf(attnl[h][kn], (float)kvs[kn][176 + t], cx);
        ctxl[t] = cx;
    }
    __syncthreads();
    // w_o projection -> concat [ctx_o | src_feat]
    if (t < DF) {
        const float4* wo4 = (const float4*)(w_o + (size_t)t * DF);
        const float4* cx4 = (const float4*)ctxl;
        float s = 0.f;
#pragma unroll 4
        for (int j = 0; j < 43; ++j) {
            float4 a = cx4[j], b = wo4[j];
            s = fmaf(a.x, b.x, s); s = fmaf(a.y, b.y, s);
            s = fmaf(a.z, b.z, s); s = fmaf(a.w, b.w, s);
        }
        catl[t] = s;
        catl[DF + t] = sf[t];
    }
    __syncthreads();
    if (t < DF) {
        const float4* w14 = (const float4*)(merge_w1 + (size_t)t * 344);
        const float4* ct4 = (const float4*)catl;
        float s = merge_b1[t];
#pragma unroll 4
        for (int j = 0; j < 86; ++j) {
            float4 a = ct4[j], b = w14[j];
            s = fmaf(a.x, b.x, s); s = fmaf(a.y, b.y, s);
            s = fmaf(a.z, b.z, s); s = fmaf(a.w, b.w, s);
        }
        h1l[t] = fmaxf(s, 0.f);
    }
    __syncthreads();
    if (t < DF) {
        const float4* w24 = (const float4*)(merge_w2 + (size_t)t * DF);
        const float4* h4  = (const float4*)h1l;
        float s = merge_b2[t];
#pragma unroll 4
        for (int j = 0; j < 43; ++j) {
            float4 a = h4[j], b = w24[j];
            s = fmaf(a.x, b.x, s); s = fmaf(a.y, b.y, s);
            s = fmaf(a.z, b.z, s); s = fmaf(a.w, b.w, s);
        }
        emb[(size_t)i * DF + t] = s;
    }
}

// ============================================================
// Kernel 4: affinity MLP -> sigmoid prob (4000 pairs)
// ============================================================
__global__ __launch_bounds__(256) void aff_kernel(
    const float* __restrict__ emb,
    const float* __restrict__ aff_w1, const float* __restrict__ aff_b1,
    const float* __restrict__ aff_w2, const float* __restrict__ aff_b2,
    float* __restrict__ out)
{
    __shared__ __align__(16) float pair[344];
    __shared__ float ahl[DF];
    __shared__ float red[4];
    const int j = blockIdx.x;
    const int t = threadIdx.x;
    const int s_idx = (j < BATCH) ? j : (j - BATCH);
    const int d_idx = (j < BATCH) ? (BATCH + j) : (2 * BATCH + (j - BATCH));
    if (t < DF) {
        pair[t]      = emb[s_idx * DF + t];
        pair[DF + t] = emb[d_idx * DF + t];
    }
    __syncthreads();
    if (t < DF) {
        const float4* w14 = (const float4*)(aff_w1 + (size_t)t * 344);
        const float4* p4  = (const float4*)pair;
        float s = aff_b1[t];
#pragma unroll 4
        for (int c = 0; c < 86; ++c) {
            float4 a = p4[c], b = w14[c];
            s = fmaf(a.x, b.x, s); s = fmaf(a.y, b.y, s);
            s = fmaf(a.z, b.z, s); s = fmaf(a.w, b.w, s);
        }
        ahl[t] = fmaxf(s, 0.f);
    }
    __syncthreads();
    float p = 0.f;
    if (t < DF) p = ahl[t] * aff_w2[t];
#pragma unroll
    for (int off = 32; off > 0; off >>= 1) p += __shfl_down(p, off, 64);
    if ((t & 63) == 0) red[t >> 6] = p;
    __syncthreads();
    if (t == 0) {
        float s = red[0] + red[1] + red[2] + red[3] + aff_b2[0];
        out[j] = 1.f / (1.f + expf(-s));
    }
}

// ============================================================
extern "C" void kernel_launch(void* const* d_in, const int* in_sizes, int n_in,
                              void* d_out, int out_size, void* d_ws, size_t ws_size,
                              hipStream_t stream)
{
    (void)in_sizes; (void)n_in; (void)out_size; (void)ws_size;
    const float* memory         = (const float*)d_in[0];
    const float* messages       = (const float*)d_in[1];
    const float* edge_features  = (const float*)d_in[2];
    const float* edge_times     = (const float*)d_in[3];
    const float* neighbor_times = (const float*)d_in[4];
    const float* time_w         = (const float*)d_in[5];
    const float* time_b         = (const float*)d_in[6];
    const float* gru_w_ih       = (const float*)d_in[7];
    const float* gru_w_hh       = (const float*)d_in[8];
    const float* gru_b_ih       = (const float*)d_in[9];
    const float* gru_b_hh       = (const float*)d_in[10];
    const float* w_q            = (const float*)d_in[11];
    const float* w_k            = (const float*)d_in[12];
    const float* w_v            = (const float*)d_in[13];
    const float* w_o            = (const float*)d_in[14];
    const float* merge_w1       = (const float*)d_in[15];
    const float* merge_b1       = (const float*)d_in[16];
    const float* merge_w2       = (const float*)d_in[17];
    const float* merge_b2       = (const float*)d_in[18];
    const float* aff_w1         = (const float*)d_in[19];
    const float* aff_b1         = (const float*)d_in[20];
    const float* aff_w2         = (const float*)d_in[21];
    const float* aff_b2         = (const float*)d_in[22];
    const int* src_nodes        = (const int*)d_in[23];
    const int* dst_nodes        = (const int*)d_in[24];
    const int* neg_nodes        = (const int*)d_in[25];
    const int* neighbors        = (const int*)d_in[26];
    const int* nbr_eidx         = (const int*)d_in[27];

    float* ws       = (float*)d_ws;
    __bf16* wpb     = (__bf16*)(ws + WPB_OFF);
    float* bp4      = ws + BP4_OFF;
    __bf16* wkvb    = (__bf16*)(ws + WKV_OFF);
    float* mem_upd  = ws + MU_OFF;
    __bf16* kv      = (__bf16*)(ws + KV_OFF);
    float* emb      = ws + EMB_OFF;
    float* out      = (float*)d_out;

    prep_kernel<<<(JP * KA + 255) / 256, 256, 0, stream>>>(
        gru_w_ih, gru_w_hh, gru_b_ih, gru_b_hh, wpb, bp4);
    prep_kv_kernel<<<(JKV * KP_KV + 255) / 256, 256, 0, stream>>>(w_k, w_v, wkvb);
    gru_mfma_kernel<<<NTILES_N * 6, 256, 0, stream>>>(
        messages, memory, wpb, bp4, mem_upd);
    kv_gemm_kernel<<<NKV_TILES * 3, 256, 0, stream>>>(
        mem_upd, edge_features, edge_times, neighbor_times, time_w, time_b,
        neighbors, nbr_eidx, wkvb, kv);
    attn_lite_kernel<<<M3, 256, 0, stream>>>(
        mem_upd, kv, time_b, w_q, w_o, merge_w1, merge_b1, merge_w2, merge_b2,
        src_nodes, dst_nodes, neg_nodes, neighbors, emb);
    aff_kernel<<<2 * BATCH, 256, 0, stream>>>(emb, aff_w1, aff_b1, aff_w2, aff_b2, out);
}

// Round 4
// 1414.491 us; speedup vs baseline: 4.6223x; 1.2900x over previous
//
#include <hip/hip_runtime.h>
#include <math.h>

// ---------------- problem constants ----------------
#define N_NODES 100000
#define BATCH   2000
#define KNBR    20
#define DF      172      // D
#define MSGD    688      // 2D + D + T
#define M3      6000     // 3*B query rows
#define DH      86       // head dim (2 heads)
#define KIN_D   516      // D + D + T  (k_in width)

// GRU GEMM (swapped operands): D(JP x NP) = W'(JP x KA) * Xb^T
#define KA      864
#define JP      768
#define KREAL   860
#define NTILES_N ((N_NODES + 127) / 128)   // 782
#define NP_ROWS (NTILES_N * 128)           // 100096 (Xb padded rows)
#define NWG_GRU (NTILES_N * 6)             // 4692

// KV GEMM: D(JKV x NKV) = Wkv'(JKV x KP_KV) * kin^T
#define NKV     120000   // 6000 * 20
#define KP_KV   544      // 516 padded to 17*32
#define JKV     384
#define KVS     352      // kv row stride bf16: [k 172|pad 4|v 172|pad 4]
#define NKV_TILES ((NKV + 127) / 128)      // 938

typedef __bf16 bf16x8 __attribute__((ext_vector_type(8)));
typedef __bf16 bf16x4 __attribute__((ext_vector_type(4)));
typedef float  f32x4  __attribute__((ext_vector_type(4)));

// ---------------- ws layout (floats) ----------------
// Xb is dead after gru GEMM; kv/emb are written after -> union them.
#define WPB_OFF 0
#define WPB_SZ  331776                       // JP*KA/2
#define BP4_OFF 331776
#define BP4_SZ  768
#define WKV_OFF 332544
#define WKV_SZ  104448                       // JKV*KP_KV/2
#define MU_OFF  436992
#define MU_SZ   17200000                     // N*DF
#define UNI_OFF 17636992
#define XB_SZ   43241472                     // NP_ROWS*KA/2
#define KV_OFF  UNI_OFF                      // overlays dead Xb
#define KV_SZ   21120000                     // NKV*KVS/2
#define EMB_OFF (UNI_OFF + KV_SZ)

__device__ __forceinline__ float sigmoidf_(float x) { return 1.0f / (1.0f + expf(-x)); }

typedef __attribute__((address_space(1))) const void gvoid;
typedef __attribute__((address_space(3))) void svoid;
__device__ __forceinline__ void gl16(const void* g, void* l) {
    __builtin_amdgcn_global_load_lds((gvoid*)g, (svoid*)l, 16, 0, 0);
}

// ============================================================
// Kernel 0a: gate-major bf16 GRU weight W' (JP x KA) + fused bias
// ============================================================
__global__ __launch_bounds__(256) void prep_kernel(
    const float* __restrict__ w_ih, const float* __restrict__ w_hh,
    const float* __restrict__ b_ih, const float* __restrict__ b_hh,
    __bf16* __restrict__ wpb, float* __restrict__ bp4)
{
    int idx = blockIdx.x * 256 + threadIdx.x;
    if (idx < JP * KA) {
        int j = idx / KA, k = idx - j * KA;
        int d = j >> 2, g = j & 3;
        float v = 0.f;
        if (d < DF) {
            if (g == 0) {
                if (k < MSGD) v = w_ih[d * MSGD + k];
                else if (k < KREAL) v = w_hh[d * DF + (k - MSGD)];
            } else if (g == 1) {
                if (k < MSGD) v = w_ih[(d + DF) * MSGD + k];
                else if (k < KREAL) v = w_hh[(d + DF) * DF + (k - MSGD)];
            } else if (g == 2) {
                if (k < MSGD) v = w_ih[(d + 2 * DF) * MSGD + k];
            } else {
                if (k >= MSGD && k < KREAL) v = w_hh[(d + 2 * DF) * DF + (k - MSGD)];
            }
        }
        wpb[idx] = (__bf16)v;
    }
    if (idx < JP) {
        int d = idx >> 2, g = idx & 3;
        float b = 0.f;
        if (d < DF) {
            if (g == 0) b = b_ih[d] + b_hh[d];
            else if (g == 1) b = b_ih[d + DF] + b_hh[d + DF];
            else if (g == 2) b = b_ih[d + 2 * DF];
            else            b = b_hh[d + 2 * DF];
        }
        bp4[idx] = b;
    }
}

// ============================================================
// Kernel 0b: combined bf16 KV weight (JKV x KP_KV)
// ============================================================
__global__ __launch_bounds__(256) void prep_kv_kernel(
    const float* __restrict__ w_k, const float* __restrict__ w_v,
    __bf16* __restrict__ wkvb)
{
    int idx = blockIdx.x * 256 + threadIdx.x;
    if (idx < JKV * KP_KV) {
        int j = idx / KP_KV, k = idx - j * KP_KV;
        float v = 0.f;
        if (k < KIN_D) {
            if (j < DF) v = w_k[j * KIN_D + k];
            else if (j >= 192 && j < 192 + DF) v = w_v[(j - 192) * KIN_D + k];
        }
        wkvb[idx] = (__bf16)v;
    }
}

// ============================================================
// Kernel 0c: X -> bf16 (Xb[NP_ROWS][KA] = [messages|memory|0])
// 8 cols per thread: 2 float4 reads -> 1 bf16x8 store.
// ============================================================
__global__ __launch_bounds__(256) void conv_kernel(
    const float* __restrict__ messages, const float* __restrict__ memory,
    __bf16* __restrict__ xb)
{
    const long total = (long)N_NODES * (KA / 8);   // 108 groups per row
    for (long idx = (long)blockIdx.x * 256 + threadIdx.x; idx < total;
         idx += (long)gridDim.x * 256) {
        const int r  = (int)(idx / (KA / 8));
        const int k  = (int)(idx - (long)r * (KA / 8)) * 8;
        float f[8];
        if (k < MSGD) {
            const float4 a = *(const float4*)(messages + (size_t)r * MSGD + k);
            const float4 b = *(const float4*)(messages + (size_t)r * MSGD + k + 4);
            f[0]=a.x; f[1]=a.y; f[2]=a.z; f[3]=a.w;
            f[4]=b.x; f[5]=b.y; f[6]=b.z; f[7]=b.w;
        } else {
            const int o = k - MSGD;                // 0,8,...,168
            const float4 a = *(const float4*)(memory + (size_t)r * DF + o);
            float4 b = make_float4(0.f, 0.f, 0.f, 0.f);
            if (o <= 164) b = *(const float4*)(memory + (size_t)r * DF + o + 4);
            f[0]=a.x; f[1]=a.y; f[2]=a.z; f[3]=a.w;
            f[4]=b.x; f[5]=b.y; f[6]=b.z; f[7]=b.w;
        }
        bf16x8 v;
#pragma unroll
        for (int j = 0; j < 8; ++j) v[j] = (__bf16)f[j];
        *(bf16x8*)(xb + (size_t)r * KA + k) = v;
    }
}

// ============================================================
// Kernel 1: MFMA GRU GEMM v2
//  128x128 tile, BK=32, global_load_lds(16B) dbuf staging, XOR slot
//  swizzle (slot ^= (row>>1)&3) pre-applied on the global source,
//  bijective XCD-chunked block swizzle (m fastest -> siblings co-XCD).
// ============================================================
__global__ __launch_bounds__(256) void gru_mfma2_kernel(
    const __bf16* __restrict__ xb, const __bf16* __restrict__ wpb,
    const float* __restrict__ bp4, const float* __restrict__ memory,
    float* __restrict__ mem_upd)
{
    __shared__ __align__(16) __bf16 Ws[2][128 * 32];
    __shared__ __align__(16) __bf16 Xs[2][128 * 32];

    const int t    = threadIdx.x;
    const int w    = t >> 6, lane = t & 63;
    const int lo   = lane & 15, hi = lane >> 4;
    const int wm   = w >> 1, wn = w & 1;

    // bijective XCD-chunked swizzle (m204): NWG_GRU = 4692, q=586, r=4
    const int orig = blockIdx.x;
    const int q = NWG_GRU >> 3, rr = NWG_GRU & 7;
    const int xcd = orig & 7, oidx = orig >> 3;
    const int wgid = (xcd < rr ? xcd * (q + 1) : rr * (q + 1) + (xcd - rr) * q) + oidx;
    const int m_tile = wgid % 6;
    const int n_tile = wgid / 6;
    const int n0 = n_tile * 128;
    const int j0 = m_tile * 128;

    // staging geometry: per wave, per tile: rows [w*32, w*32+32), 2 issues of
    // 16 rows; lane i -> row i>>2, slot i&3, src slot pre-swizzled.
    const int srow  = lane >> 2;
    const int sslot = ((lane & 3) ^ ((lane >> 3) & 3)) * 8;   // bf16 elems

    f32x4 acc[4][4];
#pragma unroll
    for (int mi = 0; mi < 4; ++mi)
#pragma unroll
        for (int ni = 0; ni < 4; ++ni)
            acc[mi][ni] = (f32x4){0.f, 0.f, 0.f, 0.f};

    const __bf16* wbase = wpb + (size_t)j0 * KA;
    const __bf16* xbase = xb + (size_t)n0 * KA;

#define STAGE(buf, k0)                                                          \
    {                                                                           \
        _Pragma("unroll")                                                       \
        for (int qq = 0; qq < 2; ++qq) {                                        \
            const int lr = w * 32 + qq * 16 + srow;                             \
            gl16(wbase + (size_t)lr * KA + (k0) + sslot,                        \
                 &Ws[buf][(w * 32 + qq * 16) * 32]);                            \
            gl16(xbase + (size_t)lr * KA + (k0) + sslot,                        \
                 &Xs[buf][(w * 32 + qq * 16) * 32]);                            \
        }                                                                       \
    }

    STAGE(0, 0);
    asm volatile("s_waitcnt vmcnt(0)" ::: "memory");
    __syncthreads();

    const int fsa = (hi ^ ((lo >> 1) & 3)) * 8;   // swizzled frag slot (elems)
    int cur = 0;
    for (int ks = 0; ks < KA / 32; ++ks) {
        if (ks + 1 < KA / 32) STAGE(cur ^ 1, (ks + 1) * 32);

        bf16x8 af[4], bx_[4];
#pragma unroll
        for (int i = 0; i < 4; ++i) {
            af[i]  = *(const bf16x8*)&Ws[cur][(wm * 64 + i * 16 + lo) * 32 + fsa];
            bx_[i] = *(const bf16x8*)&Xs[cur][(wn * 64 + i * 16 + lo) * 32 + fsa];
        }
#pragma unroll
        for (int mi = 0; mi < 4; ++mi)
#pragma unroll
            for (int ni = 0; ni < 4; ++ni)
                acc[mi][ni] = __builtin_amdgcn_mfma_f32_16x16x32_bf16(
                    af[mi], bx_[ni], acc[mi][ni], 0, 0, 0);

        asm volatile("s_waitcnt vmcnt(0)" ::: "memory");
        __syncthreads();
        cur ^= 1;
    }
#undef STAGE

    // fused GRU epilogue (lane-local: gates are regs 0..3)
    const int dbase = m_tile * 32 + wm * 16;
#pragma unroll
    for (int mi = 0; mi < 4; ++mi) {
        const int d = dbase + mi * 4 + hi;
        if (d >= DF) continue;
        const float4 b4 = *(const float4*)&bp4[4 * d];
#pragma unroll
        for (int ni = 0; ni < 4; ++ni) {
            const int n = n0 + wn * 64 + ni * 16 + lo;
            if (n >= N_NODES) continue;
            float sr  = acc[mi][ni][0] + b4.x;
            float sz  = acc[mi][ni][1] + b4.y;
            float gin = acc[mi][ni][2] + b4.z;
            float ghn = acc[mi][ni][3] + b4.w;
            float mem = memory[(size_t)n * DF + d];
            float rg  = sigmoidf_(sr);
            float zg  = sigmoidf_(sz);
            float nt  = tanhf(fmaf(rg, ghn, gin));
            mem_upd[(size_t)n * DF + d] = fmaf(zg, mem - nt, nt);
        }
    }
}

// ============================================================
// Kernel 2: batched K/V projection GEMM with on-the-fly kin build
// ============================================================
__global__ __launch_bounds__(256) void kv_gemm_kernel(
    const float* __restrict__ mem_upd, const float* __restrict__ edge_features,
    const float* __restrict__ edge_times, const float* __restrict__ neighbor_times,
    const float* __restrict__ time_w, const float* __restrict__ time_b,
    const int* __restrict__ neighbors, const int* __restrict__ nbr_eidx,
    const __bf16* __restrict__ wkvb, __bf16* __restrict__ kv)
{
    __shared__ __align__(16) __bf16 Ws[128][32];
    __shared__ __align__(16) __bf16 Xs[128][32];

    const int t    = threadIdx.x;
    const int w    = t >> 6, lane = t & 63;
    const int lo   = lane & 15, hi = lane >> 4;
    const int wm   = w >> 1, wn = w & 1;

    const int bx     = blockIdx.x;
    const int n_tile = bx / 3;
    const int m_tile = bx - n_tile * 3;
    const int n0     = n_tile * 128;
    const int j0     = m_tile * 128;

    const int xrow  = t >> 1, xhalf = t & 1;
    const int nr    = min(n0 + xrow, NKV - 1);
    const int nbr   = neighbors[nr];
    const int eidx  = nbr_eidx[nr];
    const float dt  = edge_times[(nr / KNBR) % BATCH] - neighbor_times[nr];
    const float* mrow = mem_upd       + (size_t)nbr  * DF;
    const float* erow = edge_features + (size_t)eidx * DF;
    const __bf16* wrow = wkvb + (size_t)(j0 + xrow) * KP_KV;

    f32x4 acc[4][4];
#pragma unroll
    for (int mi = 0; mi < 4; ++mi)
#pragma unroll
        for (int ni = 0; ni < 4; ++ni)
            acc[mi][ni] = (f32x4){0.f, 0.f, 0.f, 0.f};

    for (int k0 = 0; k0 < KP_KV; k0 += 32) {
        bf16x8 w0 = *(const bf16x8*)(wrow + k0 + xhalf * 16);
        bf16x8 w1 = *(const bf16x8*)(wrow + k0 + xhalf * 16 + 8);
        float fl[16];
#pragma unroll
        for (int c = 0; c < 4; ++c) {
            const int kb = k0 + xhalf * 16 + c * 4;
            float4 v;
            if (kb < DF) {
                v = *(const float4*)(mrow + kb);
            } else if (kb < 2 * DF) {
                v = *(const float4*)(erow + (kb - DF));
            } else if (kb < KIN_D) {
                const float4 tw = *(const float4*)(time_w + (kb - 2 * DF));
                const float4 tb = *(const float4*)(time_b + (kb - 2 * DF));
                v.x = cosf(fmaf(dt, tw.x, tb.x));
                v.y = cosf(fmaf(dt, tw.y, tb.y));
                v.z = cosf(fmaf(dt, tw.z, tb.z));
                v.w = cosf(fmaf(dt, tw.w, tb.w));
            } else {
                v = make_float4(0.f, 0.f, 0.f, 0.f);
            }
            fl[c * 4 + 0] = v.x; fl[c * 4 + 1] = v.y;
            fl[c * 4 + 2] = v.z; fl[c * 4 + 3] = v.w;
        }
        bf16x8 x0, x1;
#pragma unroll
        for (int jj = 0; jj < 8; ++jj) {
            x0[jj] = (__bf16)fl[jj];
            x1[jj] = (__bf16)fl[8 + jj];
        }
        *(bf16x8*)&Ws[xrow][xhalf * 16]     = w0;
        *(bf16x8*)&Ws[xrow][xhalf * 16 + 8] = w1;
        *(bf16x8*)&Xs[xrow][xhalf * 16]     = x0;
        *(bf16x8*)&Xs[xrow][xhalf * 16 + 8] = x1;
        __syncthreads();

        bf16x8 af[4], bx_[4];
#pragma unroll
        for (int i = 0; i < 4; ++i) {
            af[i]  = *(const bf16x8*)&Ws[wm * 64 + i * 16 + lo][hi * 8];
            bx_[i] = *(const bf16x8*)&Xs[wn * 64 + i * 16 + lo][hi * 8];
        }
#pragma unroll
        for (int mi = 0; mi < 4; ++mi)
#pragma unroll
            for (int ni = 0; ni < 4; ++ni)
                acc[mi][ni] = __builtin_amdgcn_mfma_f32_16x16x32_bf16(
                    af[mi], bx_[ni], acc[mi][ni], 0, 0, 0);
        __syncthreads();
    }

#pragma unroll
    for (int mi = 0; mi < 4; ++mi) {
        const int jb = j0 + wm * 64 + mi * 16 + hi * 4;
        int off;
        if (jb + 3 < DF)                 off = jb;
        else if (jb >= 192 && jb < 361)  off = jb - 16;
        else continue;
#pragma unroll
        for (int ni = 0; ni < 4; ++ni) {
            const int n = n0 + wn * 64 + ni * 16 + lo;
            if (n >= NKV) continue;
            bf16x4 o;
            o[0] = (__bf16)acc[mi][ni][0];
            o[1] = (__bf16)acc[mi][ni][1];
            o[2] = (__bf16)acc[mi][ni][2];
            o[3] = (__bf16)acc[mi][ni][3];
            *(bf16x4*)(kv + (size_t)n * KVS + off) = o;
        }
    }
}

// ============================================================
// Kernel 3: per-query attention (reads precomputed KV) + merge MLP
// ============================================================
__global__ __launch_bounds__(256) void attn_lite_kernel(
    const float* __restrict__ mem_upd, const __bf16* __restrict__ kv,
    const float* __restrict__ time_b,
    const float* __restrict__ w_q, const float* __restrict__ w_o,
    const float* __restrict__ merge_w1, const float* __restrict__ merge_b1,
    const float* __restrict__ merge_w2, const float* __restrict__ merge_b2,
    const int* __restrict__ src_nodes, const int* __restrict__ dst_nodes,
    const int* __restrict__ neg_nodes, const int* __restrict__ neighbors,
    float* __restrict__ emb)
{
    __shared__ __align__(16) __bf16 kvs[KNBR][KVS];
    __shared__ __align__(16) float qin[344];
    __shared__ __align__(16) float qv[DF];
    __shared__ __align__(16) float ctxl[DF];
    __shared__ __align__(16) float catl[344];
    __shared__ __align__(16) float h1l[DF];
    __shared__ float sf[DF];
    __shared__ float scl[2][KNBR];
    __shared__ float attnl[2][KNBR];
    __shared__ int   nbrs[KNBR];

    const int i = blockIdx.x;
    const int t = threadIdx.x;

    int node;
    if (i < BATCH)          node = src_nodes[i];
    else if (i < 2 * BATCH) node = dst_nodes[i - BATCH];
    else                    node = neg_nodes[i - 2 * BATCH];

    if (t < KNBR) nbrs[t] = neighbors[i * KNBR + t];
    if (t < DF) {
        float v = mem_upd[(size_t)node * DF + t];
        sf[t] = v;
        qin[t] = v;
        qin[DF + t] = cosf(time_b[t]);
    }
    {
        const uint4* src = (const uint4*)(kv + (size_t)i * KNBR * KVS);
        uint4* dst = (uint4*)&kvs[0][0];
        for (int idx = t; idx < KNBR * KVS / 8; idx += 256) dst[idx] = src[idx];
    }
    __syncthreads();

    if (t < DF) {
        const float4* wq4 = (const float4*)(w_q + (size_t)t * 344);
        const float4* qi4 = (const float4*)qin;
        float s = 0.f;
#pragma unroll 4
        for (int j = 0; j < 86; ++j) {
            float4 a = qi4[j], b = wq4[j];
            s = fmaf(a.x, b.x, s); s = fmaf(a.y, b.y, s);
            s = fmaf(a.z, b.z, s); s = fmaf(a.w, b.w, s);
        }
        qv[t] = s;
    }
    __syncthreads();

    if (t < 2 * KNBR) {
        int h = t / KNBR, kn = t - h * KNBR;
        float s = 0.f;
#pragma unroll 2
        for (int j = 0; j < DH; ++j)
            s = fmaf(qv[h * DH + j], (float)kvs[kn][h * DH + j], s);
        s /= sqrtf((float)DH);
        scl[h][kn] = (nbrs[kn] > 0) ? s : -1e9f;
    }
    __syncthreads();
    if (t < 2) {
        float m = -INFINITY;
        for (int kn = 0; kn < KNBR; ++kn) m = fmaxf(m, scl[t][kn]);
        float se = 0.f;
        for (int kn = 0; kn < KNBR; ++kn) se += expf(scl[t][kn] - m);
        float inv = 1.f / se;
        for (int kn = 0; kn < KNBR; ++kn) attnl[t][kn] = expf(scl[t][kn] - m) * inv;
    }
    __syncthreads();
    if (t < DF) {
        int h = t / DH;
        float cx = 0.f;
#pragma unroll
        for (int kn = 0; kn < KNBR; ++kn)
            cx = fmaf(attnl[h][kn], (float)kvs[kn][176 + t], cx);
        ctxl[t] = cx;
    }
    __syncthreads();
    if (t < DF) {
        const float4* wo4 = (const float4*)(w_o + (size_t)t * DF);
        const float4* cx4 = (const float4*)ctxl;
        float s = 0.f;
#pragma unroll 4
        for (int j = 0; j < 43; ++j) {
            float4 a = cx4[j], b = wo4[j];
            s = fmaf(a.x, b.x, s); s = fmaf(a.y, b.y, s);
            s = fmaf(a.z, b.z, s); s = fmaf(a.w, b.w, s);
        }
        catl[t] = s;
        catl[DF + t] = sf[t];
    }
    __syncthreads();
    if (t < DF) {
        const float4* w14 = (const float4*)(merge_w1 + (size_t)t * 344);
        const float4* ct4 = (const float4*)catl;
        float s = merge_b1[t];
#pragma unroll 4
        for (int j = 0; j < 86; ++j) {
            float4 a = ct4[j], b = w14[j];
            s = fmaf(a.x, b.x, s); s = fmaf(a.y, b.y, s);
            s = fmaf(a.z, b.z, s); s = fmaf(a.w, b.w, s);
        }
        h1l[t] = fmaxf(s, 0.f);
    }
    __syncthreads();
    if (t < DF) {
        const float4* w24 = (const float4*)(merge_w2 + (size_t)t * DF);
        const float4* h4  = (const float4*)h1l;
        float s = merge_b2[t];
#pragma unroll 4
        for (int j = 0; j < 43; ++j) {
            float4 a = h4[j], b = w24[j];
            s = fmaf(a.x, b.x, s); s = fmaf(a.y, b.y, s);
            s = fmaf(a.z, b.z, s); s = fmaf(a.w, b.w, s);
        }
        emb[(size_t)i * DF + t] = s;
    }
}

// ============================================================
// Kernel 4: affinity MLP -> sigmoid prob (4000 pairs)
// ============================================================
__global__ __launch_bounds__(256) void aff_kernel(
    const float* __restrict__ emb,
    const float* __restrict__ aff_w1, const float* __restrict__ aff_b1,
    const float* __restrict__ aff_w2, const float* __restrict__ aff_b2,
    float* __restrict__ out)
{
    __shared__ __align__(16) float pair[344];
    __shared__ float ahl[DF];
    __shared__ float red[4];
    const int j = blockIdx.x;
    const int t = threadIdx.x;
    const int s_idx = (j < BATCH) ? j : (j - BATCH);
    const int d_idx = (j < BATCH) ? (BATCH + j) : (2 * BATCH + (j - BATCH));
    if (t < DF) {
        pair[t]      = emb[s_idx * DF + t];
        pair[DF + t] = emb[d_idx * DF + t];
    }
    __syncthreads();
    if (t < DF) {
        const float4* w14 = (const float4*)(aff_w1 + (size_t)t * 344);
        const float4* p4  = (const float4*)pair;
        float s = aff_b1[t];
#pragma unroll 4
        for (int c = 0; c < 86; ++c) {
            float4 a = p4[c], b = w14[c];
            s = fmaf(a.x, b.x, s); s = fmaf(a.y, b.y, s);
            s = fmaf(a.z, b.z, s); s = fmaf(a.w, b.w, s);
        }
        ahl[t] = fmaxf(s, 0.f);
    }
    __syncthreads();
    float p = 0.f;
    if (t < DF) p = ahl[t] * aff_w2[t];
#pragma unroll
    for (int off = 32; off > 0; off >>= 1) p += __shfl_down(p, off, 64);
    if ((t & 63) == 0) red[t >> 6] = p;
    __syncthreads();
    if (t == 0) {
        float s = red[0] + red[1] + red[2] + red[3] + aff_b2[0];
        out[j] = 1.f / (1.f + expf(-s));
    }
}

// ============================================================
extern "C" void kernel_launch(void* const* d_in, const int* in_sizes, int n_in,
                              void* d_out, int out_size, void* d_ws, size_t ws_size,
                              hipStream_t stream)
{
    (void)in_sizes; (void)n_in; (void)out_size; (void)ws_size;
    const float* memory         = (const float*)d_in[0];
    const float* messages       = (const float*)d_in[1];
    const float* edge_features  = (const float*)d_in[2];
    const float* edge_times     = (const float*)d_in[3];
    const float* neighbor_times = (const float*)d_in[4];
    const float* time_w         = (const float*)d_in[5];
    const float* time_b         = (const float*)d_in[6];
    const float* gru_w_ih       = (const float*)d_in[7];
    const float* gru_w_hh       = (const float*)d_in[8];
    const float* gru_b_ih       = (const float*)d_in[9];
    const float* gru_b_hh       = (const float*)d_in[10];
    const float* w_q            = (const float*)d_in[11];
    const float* w_k            = (const float*)d_in[12];
    const float* w_v            = (const float*)d_in[13];
    const float* w_o            = (const float*)d_in[14];
    const float* merge_w1       = (const float*)d_in[15];
    const float* merge_b1       = (const float*)d_in[16];
    const float* merge_w2       = (const float*)d_in[17];
    const float* merge_b2       = (const float*)d_in[18];
    const float* aff_w1         = (const float*)d_in[19];
    const float* aff_b1         = (const float*)d_in[20];
    const float* aff_w2         = (const float*)d_in[21];
    const float* aff_b2         = (const float*)d_in[22];
    const int* src_nodes        = (const int*)d_in[23];
    const int* dst_nodes        = (const int*)d_in[24];
    const int* neg_nodes        = (const int*)d_in[25];
    const int* neighbors        = (const int*)d_in[26];
    const int* nbr_eidx         = (const int*)d_in[27];

    float* ws       = (float*)d_ws;
    __bf16* wpb     = (__bf16*)(ws + WPB_OFF);
    float* bp4      = ws + BP4_OFF;
    __bf16* wkvb    = (__bf16*)(ws + WKV_OFF);
    float* mem_upd  = ws + MU_OFF;
    __bf16* xbuf    = (__bf16*)(ws + UNI_OFF);
    __bf16* kv      = (__bf16*)(ws + KV_OFF);
    float* emb      = ws + EMB_OFF;
    float* out      = (float*)d_out;

    prep_kernel<<<(JP * KA + 255) / 256, 256, 0, stream>>>(
        gru_w_ih, gru_w_hh, gru_b_ih, gru_b_hh, wpb, bp4);
    prep_kv_kernel<<<(JKV * KP_KV + 255) / 256, 256, 0, stream>>>(w_k, w_v, wkvb);
    conv_kernel<<<2048, 256, 0, stream>>>(messages, memory, xbuf);
    gru_mfma2_kernel<<<NWG_GRU, 256, 0, stream>>>(
        xbuf, wpb, bp4, memory, mem_upd);
    kv_gemm_kernel<<<NKV_TILES * 3, 256, 0, stream>>>(
        mem_upd, edge_features, edge_times, neighbor_times, time_w, time_b,
        neighbors, nbr_eidx, wkvb, kv);
    attn_lite_kernel<<<M3, 256, 0, stream>>>(
        mem_upd, kv, time_b, w_q, w_o, merge_w1, merge_b1, merge_w2, merge_b2,
        src_nodes, dst_nodes, neg_nodes, neighbors, emb);
    aff_kernel<<<2 * BATCH, 256, 0, stream>>>(emb, aff_w1, aff_b1, aff_w2, aff_b2, out);
}

// Round 5
// 920.266 us; speedup vs baseline: 7.1047x; 1.5370x over previous
//
#include <hip/hip_runtime.h>
#include <math.h>

// ---------------- problem constants ----------------
#define N_NODES 100000
#define BATCH   2000
#define KNBR    20
#define DF      172
#define MSGD    688
#define M3      6000
#define DH      86
#define KIN_D   516

// GRU GEMM
#define KA      864
#define JP      768
#define KREAL   860
#define NTILES_N ((N_NODES + 127) / 128)   // 782
#define NWG_GRU (NTILES_N * 6)             // 4692

// KV GEMM
#define NKV     120000
#define KP_KV   544
#define JKV     384
#define KVS     352
#define NKV_TILES ((NKV + 127) / 128)

typedef __bf16 bf16x8 __attribute__((ext_vector_type(8)));
typedef __bf16 bf16x4 __attribute__((ext_vector_type(4)));
typedef float  f32x4  __attribute__((ext_vector_type(4)));

// ---------------- ws layout (floats) ----------------
#define WPB_OFF   0
#define BP4_OFF   331776
#define WKV_OFF   332544
#define MU_OFF    436992
#define UNI_OFF   17636992          // Xb region (dead after gru); unions below
#define KV_OFF    UNI_OFF           // +21120000
#define QB_OFF    38756992          // bf16 6016x176
#define CAT_OFF   39286400          // bf16 6016x352
#define H1_OFF    40345216          // bf16 6016x192
#define EMBB_OFF  40922752          // bf16 6016x176
#define AH_OFF    41452160          // bf16 4096x176
#define MW1O_OFF  41812608          // f32 172x172
#define WQB_OFF   41842192          // bf16 192x352
#define WM1B_OFF  41875984          // bf16 192x352
#define WM2B_OFF  41909776          // bf16 192x192
#define WAFFB_OFF 41928208          // bf16 192x352
#define BM1P_OFF  41962000
#define BM2P_OFF  41962192
#define BAFFP_OFF 41962384
#define BQ0_OFF   41962576
#define NODES_OFF 41962768          // int 6016

__device__ __forceinline__ float sigmoidf_(float x) { return 1.0f / (1.0f + expf(-x)); }

typedef __attribute__((address_space(1))) const void gvoid;
typedef __attribute__((address_space(3))) void svoid;
__device__ __forceinline__ void gl16(const void* g, void* l) {
    __builtin_amdgcn_global_load_lds((gvoid*)g, (svoid*)l, 16, 0, 0);
}

// ============================================================
// Kernel 0a: gate-major bf16 GRU weight W' (JP x KA) + fused bias
// ============================================================
__global__ __launch_bounds__(256) void prep_kernel(
    const float* __restrict__ w_ih, const float* __restrict__ w_hh,
    const float* __restrict__ b_ih, const float* __restrict__ b_hh,
    __bf16* __restrict__ wpb, float* __restrict__ bp4)
{
    int idx = blockIdx.x * 256 + threadIdx.x;
    if (idx < JP * KA) {
        int j = idx / KA, k = idx - j * KA;
        int d = j >> 2, g = j & 3;
        float v = 0.f;
        if (d < DF) {
            if (g == 0) {
                if (k < MSGD) v = w_ih[d * MSGD + k];
                else if (k < KREAL) v = w_hh[d * DF + (k - MSGD)];
            } else if (g == 1) {
                if (k < MSGD) v = w_ih[(d + DF) * MSGD + k];
                else if (k < KREAL) v = w_hh[(d + DF) * DF + (k - MSGD)];
            } else if (g == 2) {
                if (k < MSGD) v = w_ih[(d + 2 * DF) * MSGD + k];
            } else {
                if (k >= MSGD && k < KREAL) v = w_hh[(d + 2 * DF) * DF + (k - MSGD)];
            }
        }
        wpb[idx] = (__bf16)v;
    }
    if (idx < JP) {
        int d = idx >> 2, g = idx & 3;
        float b = 0.f;
        if (d < DF) {
            if (g == 0) b = b_ih[d] + b_hh[d];
            else if (g == 1) b = b_ih[d + DF] + b_hh[d + DF];
            else if (g == 2) b = b_ih[d + 2 * DF];
            else            b = b_hh[d + 2 * DF];
        }
        bp4[idx] = b;
    }
}

// ============================================================
// Kernel 0b: combined bf16 KV weight (JKV x KP_KV)
// ============================================================
__global__ __launch_bounds__(256) void prep_kv_kernel(
    const float* __restrict__ w_k, const float* __restrict__ w_v,
    __bf16* __restrict__ wkvb)
{
    int idx = blockIdx.x * 256 + threadIdx.x;
    if (idx < JKV * KP_KV) {
        int j = idx / KP_KV, k = idx - j * KP_KV;
        float v = 0.f;
        if (k < KIN_D) {
            if (j < DF) v = w_k[j * KIN_D + k];
            else if (j >= 192 && j < 192 + DF) v = w_v[(j - 192) * KIN_D + k];
        }
        wkvb[idx] = (__bf16)v;
    }
}

// ============================================================
// Kernel 0c: X -> bf16
// ============================================================
__global__ __launch_bounds__(256) void conv_kernel(
    const float* __restrict__ messages, const float* __restrict__ memory,
    __bf16* __restrict__ xb)
{
    const long total = (long)N_NODES * (KA / 8);
    for (long idx = (long)blockIdx.x * 256 + threadIdx.x; idx < total;
         idx += (long)gridDim.x * 256) {
        const int r  = (int)(idx / (KA / 8));
        const int k  = (int)(idx - (long)r * (KA / 8)) * 8;
        float f[8];
        if (k < MSGD) {
            const float4 a = *(const float4*)(messages + (size_t)r * MSGD + k);
            const float4 b = *(const float4*)(messages + (size_t)r * MSGD + k + 4);
            f[0]=a.x; f[1]=a.y; f[2]=a.z; f[3]=a.w;
            f[4]=b.x; f[5]=b.y; f[6]=b.z; f[7]=b.w;
        } else {
            const int o = k - MSGD;
            const float4 a = *(const float4*)(memory + (size_t)r * DF + o);
            float4 b = make_float4(0.f, 0.f, 0.f, 0.f);
            if (o <= 164) b = *(const float4*)(memory + (size_t)r * DF + o + 4);
            f[0]=a.x; f[1]=a.y; f[2]=a.z; f[3]=a.w;
            f[4]=b.x; f[5]=b.y; f[6]=b.z; f[7]=b.w;
        }
        bf16x8 v;
#pragma unroll
        for (int j = 0; j < 8; ++j) v[j] = (__bf16)f[j];
        *(bf16x8*)(xb + (size_t)r * KA + k) = v;
    }
}

// ============================================================
// Kernel 0d: mw1o = merge_w1[:, :172] @ w_o   (172x172 f32)
// ============================================================
__global__ __launch_bounds__(256) void mw1o_kernel(
    const float* __restrict__ merge_w1, const float* __restrict__ w_o,
    float* __restrict__ mw1o)
{
    int idx = blockIdx.x * 256 + threadIdx.x;
    if (idx >= DF * DF) return;
    int j = idx / DF, k = idx - j * DF;
    float s = 0.f;
    for (int c = 0; c < DF; ++c)
        s = fmaf(merge_w1[j * 344 + c], w_o[c * DF + k], s);
    mw1o[idx] = s;
}

// ============================================================
// Kernel 0e: tail weights/biases/nodes_cat
// ============================================================
__global__ __launch_bounds__(256) void prep_tail_kernel(
    const float* __restrict__ w_q, const float* __restrict__ mw1o,
    const float* __restrict__ merge_w1, const float* __restrict__ merge_w2,
    const float* __restrict__ aff_w1,
    const float* __restrict__ merge_b1, const float* __restrict__ merge_b2,
    const float* __restrict__ aff_b1,
    const int* __restrict__ src_nodes, const int* __restrict__ dst_nodes,
    const int* __restrict__ neg_nodes,
    __bf16* __restrict__ wqb, __bf16* __restrict__ wm1b,
    __bf16* __restrict__ wm2b, __bf16* __restrict__ waffb,
    float* __restrict__ bm1p, float* __restrict__ bm2p,
    float* __restrict__ baffp, float* __restrict__ bq0,
    int* __restrict__ nodes_cat)
{
    int idx = blockIdx.x * 256 + threadIdx.x;
    if (idx < 192 * 352) {
        int j = idx / 352, k = idx - j * 352;
        float vq = 0.f, vm = 0.f, va = 0.f;
        if (j < DF) {
            if (k < DF) {
                vq = w_q[j * 344 + k];
                vm = mw1o[j * DF + k];
                va = aff_w1[j * 344 + k];
            } else if (k >= 176 && k < 348) {
                vq = w_q[j * 344 + 172 + (k - 176)];
                vm = merge_w1[j * 344 + 172 + (k - 176)];
                va = aff_w1[j * 344 + 172 + (k - 176)];
            }
        }
        wqb[idx] = (__bf16)vq;
        wm1b[idx] = (__bf16)vm;
        waffb[idx] = (__bf16)va;
    }
    if (idx < 192 * 192) {
        int j = idx / 192, k = idx - j * 192;
        wm2b[idx] = (__bf16)((j < DF && k < DF) ? merge_w2[j * DF + k] : 0.f);
    }
    if (idx < 192) {
        bm1p[idx]  = (idx < DF) ? merge_b1[idx] : 0.f;
        bm2p[idx]  = (idx < DF) ? merge_b2[idx] : 0.f;
        baffp[idx] = (idx < DF) ? aff_b1[idx] : 0.f;
        bq0[idx]   = 0.f;
    }
    if (idx < 6016) {
        int i = min(idx, M3 - 1);
        int node;
        if (i < BATCH)          node = src_nodes[i];
        else if (i < 2 * BATCH) node = dst_nodes[i - BATCH];
        else                    node = neg_nodes[i - 2 * BATCH];
        nodes_cat[idx] = node;
    }
}

// ============================================================
// Kernel 1: MFMA GRU GEMM v2 (unchanged from R4)
// ============================================================
__global__ __launch_bounds__(256) void gru_mfma2_kernel(
    const __bf16* __restrict__ xb, const __bf16* __restrict__ wpb,
    const float* __restrict__ bp4, const float* __restrict__ memory,
    float* __restrict__ mem_upd)
{
    __shared__ __align__(16) __bf16 Ws[2][128 * 32];
    __shared__ __align__(16) __bf16 Xs[2][128 * 32];

    const int t    = threadIdx.x;
    const int w    = t >> 6, lane = t & 63;
    const int lo   = lane & 15, hi = lane >> 4;
    const int wm   = w >> 1, wn = w & 1;

    const int orig = blockIdx.x;
    const int q = NWG_GRU >> 3, rr = NWG_GRU & 7;
    const int xcd = orig & 7, oidx = orig >> 3;
    const int wgid = (xcd < rr ? xcd * (q + 1) : rr * (q + 1) + (xcd - rr) * q) + oidx;
    const int m_tile = wgid % 6;
    const int n_tile = wgid / 6;
    const int n0 = n_tile * 128;
    const int j0 = m_tile * 128;

    const int srow  = lane >> 2;
    const int sslot = ((lane & 3) ^ ((lane >> 3) & 3)) * 8;

    f32x4 acc[4][4];
#pragma unroll
    for (int mi = 0; mi < 4; ++mi)
#pragma unroll
        for (int ni = 0; ni < 4; ++ni)
            acc[mi][ni] = (f32x4){0.f, 0.f, 0.f, 0.f};

    const __bf16* wbase = wpb + (size_t)j0 * KA;
    const __bf16* xbase = xb + (size_t)n0 * KA;

#define STAGE(buf, k0)                                                          \
    {                                                                           \
        _Pragma("unroll")                                                       \
        for (int qq = 0; qq < 2; ++qq) {                                        \
            const int lr = w * 32 + qq * 16 + srow;                             \
            gl16(wbase + (size_t)lr * KA + (k0) + sslot,                        \
                 &Ws[buf][(w * 32 + qq * 16) * 32]);                            \
            gl16(xbase + (size_t)lr * KA + (k0) + sslot,                        \
                 &Xs[buf][(w * 32 + qq * 16) * 32]);                            \
        }                                                                       \
    }

    STAGE(0, 0);
    asm volatile("s_waitcnt vmcnt(0)" ::: "memory");
    __syncthreads();

    const int fsa = (hi ^ ((lo >> 1) & 3)) * 8;
    int cur = 0;
    for (int ks = 0; ks < KA / 32; ++ks) {
        if (ks + 1 < KA / 32) STAGE(cur ^ 1, (ks + 1) * 32);

        bf16x8 af[4], bx_[4];
#pragma unroll
        for (int i = 0; i < 4; ++i) {
            af[i]  = *(const bf16x8*)&Ws[cur][(wm * 64 + i * 16 + lo) * 32 + fsa];
            bx_[i] = *(const bf16x8*)&Xs[cur][(wn * 64 + i * 16 + lo) * 32 + fsa];
        }
#pragma unroll
        for (int mi = 0; mi < 4; ++mi)
#pragma unroll
            for (int ni = 0; ni < 4; ++ni)
                acc[mi][ni] = __builtin_amdgcn_mfma_f32_16x16x32_bf16(
                    af[mi], bx_[ni], acc[mi][ni], 0, 0, 0);

        asm volatile("s_waitcnt vmcnt(0)" ::: "memory");
        __syncthreads();
        cur ^= 1;
    }
#undef STAGE

    const int dbase = m_tile * 32 + wm * 16;
#pragma unroll
    for (int mi = 0; mi < 4; ++mi) {
        const int d = dbase + mi * 4 + hi;
        if (d >= DF) continue;
        const float4 b4 = *(const float4*)&bp4[4 * d];
#pragma unroll
        for (int ni = 0; ni < 4; ++ni) {
            const int n = n0 + wn * 64 + ni * 16 + lo;
            if (n >= N_NODES) continue;
            float sr  = acc[mi][ni][0] + b4.x;
            float sz  = acc[mi][ni][1] + b4.y;
            float gin = acc[mi][ni][2] + b4.z;
            float ghn = acc[mi][ni][3] + b4.w;
            float mem = memory[(size_t)n * DF + d];
            float rg  = sigmoidf_(sr);
            float zg  = sigmoidf_(sz);
            float nt  = tanhf(fmaf(rg, ghn, gin));
            mem_upd[(size_t)n * DF + d] = fmaf(zg, mem - nt, nt);
        }
    }
}

// ============================================================
// Kernel 2: batched K/V projection GEMM (unchanged from R3/R4)
// ============================================================
__global__ __launch_bounds__(256) void kv_gemm_kernel(
    const float* __restrict__ mem_upd, const float* __restrict__ edge_features,
    const float* __restrict__ edge_times, const float* __restrict__ neighbor_times,
    const float* __restrict__ time_w, const float* __restrict__ time_b,
    const int* __restrict__ neighbors, const int* __restrict__ nbr_eidx,
    const __bf16* __restrict__ wkvb, __bf16* __restrict__ kv)
{
    __shared__ __align__(16) __bf16 Ws[128][32];
    __shared__ __align__(16) __bf16 Xs[128][32];

    const int t    = threadIdx.x;
    const int w    = t >> 6, lane = t & 63;
    const int lo   = lane & 15, hi = lane >> 4;
    const int wm   = w >> 1, wn = w & 1;

    const int bx     = blockIdx.x;
    const int n_tile = bx / 3;
    const int m_tile = bx - n_tile * 3;
    const int n0     = n_tile * 128;
    const int j0     = m_tile * 128;

    const int xrow  = t >> 1, xhalf = t & 1;
    const int nr    = min(n0 + xrow, NKV - 1);
    const int nbr   = neighbors[nr];
    const int eidx  = nbr_eidx[nr];
    const float dt  = edge_times[(nr / KNBR) % BATCH] - neighbor_times[nr];
    const float* mrow = mem_upd       + (size_t)nbr  * DF;
    const float* erow = edge_features + (size_t)eidx * DF;
    const __bf16* wrow = wkvb + (size_t)(j0 + xrow) * KP_KV;

    f32x4 acc[4][4];
#pragma unroll
    for (int mi = 0; mi < 4; ++mi)
#pragma unroll
        for (int ni = 0; ni < 4; ++ni)
            acc[mi][ni] = (f32x4){0.f, 0.f, 0.f, 0.f};

    for (int k0 = 0; k0 < KP_KV; k0 += 32) {
        bf16x8 w0 = *(const bf16x8*)(wrow + k0 + xhalf * 16);
        bf16x8 w1 = *(const bf16x8*)(wrow + k0 + xhalf * 16 + 8);
        float fl[16];
#pragma unroll
        for (int c = 0; c < 4; ++c) {
            const int kb = k0 + xhalf * 16 + c * 4;
            float4 v;
            if (kb < DF) {
                v = *(const float4*)(mrow + kb);
            } else if (kb < 2 * DF) {
                v = *(const float4*)(erow + (kb - DF));
            } else if (kb < KIN_D) {
                const float4 tw = *(const float4*)(time_w + (kb - 2 * DF));
                const float4 tb = *(const float4*)(time_b + (kb - 2 * DF));
                v.x = cosf(fmaf(dt, tw.x, tb.x));
                v.y = cosf(fmaf(dt, tw.y, tb.y));
                v.z = cosf(fmaf(dt, tw.z, tb.z));
                v.w = cosf(fmaf(dt, tw.w, tb.w));
            } else {
                v = make_float4(0.f, 0.f, 0.f, 0.f);
            }
            fl[c * 4 + 0] = v.x; fl[c * 4 + 1] = v.y;
            fl[c * 4 + 2] = v.z; fl[c * 4 + 3] = v.w;
        }
        bf16x8 x0, x1;
#pragma unroll
        for (int jj = 0; jj < 8; ++jj) {
            x0[jj] = (__bf16)fl[jj];
            x1[jj] = (__bf16)fl[8 + jj];
        }
        *(bf16x8*)&Ws[xrow][xhalf * 16]     = w0;
        *(bf16x8*)&Ws[xrow][xhalf * 16 + 8] = w1;
        *(bf16x8*)&Xs[xrow][xhalf * 16]     = x0;
        *(bf16x8*)&Xs[xrow][xhalf * 16 + 8] = x1;
        __syncthreads();

        bf16x8 af[4], bx_[4];
#pragma unroll
        for (int i = 0; i < 4; ++i) {
            af[i]  = *(const bf16x8*)&Ws[wm * 64 + i * 16 + lo][hi * 8];
            bx_[i] = *(const bf16x8*)&Xs[wn * 64 + i * 16 + lo][hi * 8];
        }
#pragma unroll
        for (int mi = 0; mi < 4; ++mi)
#pragma unroll
            for (int ni = 0; ni < 4; ++ni)
                acc[mi][ni] = __builtin_amdgcn_mfma_f32_16x16x32_bf16(
                    af[mi], bx_[ni], acc[mi][ni], 0, 0, 0);
        __syncthreads();
    }

#pragma unroll
    for (int mi = 0; mi < 4; ++mi) {
        const int jb = j0 + wm * 64 + mi * 16 + hi * 4;
        int off;
        if (jb + 3 < DF)                 off = jb;
        else if (jb >= 192 && jb < 361)  off = jb - 16;
        else continue;
#pragma unroll
        for (int ni = 0; ni < 4; ++ni) {
            const int n = n0 + wn * 64 + ni * 16 + lo;
            if (n >= NKV) continue;
            bf16x4 o;
            o[0] = (__bf16)acc[mi][ni][0];
            o[1] = (__bf16)acc[mi][ni][1];
            o[2] = (__bf16)acc[mi][ni][2];
            o[3] = (__bf16)acc[mi][ni][3];
            *(bf16x4*)(kv + (size_t)n * KVS + off) = o;
        }
    }
}

// ============================================================
// Generic tail GEMM: D(192 x nrows) = W(192 x KP) * act^T, bf16 out.
//  MODE 0: act row = [mem_upd[nodes_cat[n]] | pad | cos(time_b) | pad] (f32 src)
//  MODE 1: act = bf16 rows, stride KP
//  MODE 2: act row = [embb[s(n)] (176) | embb[d(n)] (176)] bf16
//  Two overlapping m-tiles (j0 = 0 / 64); duplicate writes are identical.
// ============================================================
template<int MODE, int KP>
__global__ __launch_bounds__(256) void tail_gemm_kernel(
    const __bf16* __restrict__ wb, const float* __restrict__ bias,
    const void* __restrict__ actsrc, const float* __restrict__ time_b,
    const int* __restrict__ nodes_cat,
    __bf16* __restrict__ outb, int ostride, int jmax, int nrows, int relu)
{
    __shared__ __align__(16) __bf16 Ws[128][32];
    __shared__ __align__(16) __bf16 Xs[128][32];

    const int t    = threadIdx.x;
    const int w    = t >> 6, lane = t & 63;
    const int lo   = lane & 15, hi = lane >> 4;
    const int wm   = w >> 1, wn = w & 1;

    const int n_tile = blockIdx.x >> 1;
    const int j0     = (blockIdx.x & 1) * 64;
    const int n0     = n_tile * 128;

    const int xrow  = t >> 1, xhalf = t & 1;
    const int nr    = min(n0 + xrow, nrows - 1);
    const __bf16* wrow = wb + (size_t)(j0 + xrow) * KP;

    f32x4 acc[4][4];
#pragma unroll
    for (int mi = 0; mi < 4; ++mi)
#pragma unroll
        for (int ni = 0; ni < 4; ++ni)
            acc[mi][ni] = (f32x4){0.f, 0.f, 0.f, 0.f};

    for (int k0 = 0; k0 < KP; k0 += 32) {
        bf16x8 w0 = *(const bf16x8*)(wrow + k0 + xhalf * 16);
        bf16x8 w1 = *(const bf16x8*)(wrow + k0 + xhalf * 16 + 8);
        bf16x8 x0, x1;
        const int kb16 = k0 + xhalf * 16;
        if constexpr (MODE == 0) {
            const float* mrow = (const float*)actsrc + (size_t)nodes_cat[nr] * DF;
            float fl[16];
#pragma unroll
            for (int c = 0; c < 4; ++c) {
                const int b = kb16 + c * 4;
                float4 v;
                if (b + 3 < DF) v = *(const float4*)(mrow + b);
                else if (b >= 176 && b < 348) {
                    const float4 tb = *(const float4*)(time_b + (b - 176));
                    v.x = cosf(tb.x); v.y = cosf(tb.y);
                    v.z = cosf(tb.z); v.w = cosf(tb.w);
                } else v = make_float4(0.f, 0.f, 0.f, 0.f);
                fl[c*4+0]=v.x; fl[c*4+1]=v.y; fl[c*4+2]=v.z; fl[c*4+3]=v.w;
            }
#pragma unroll
            for (int jj = 0; jj < 8; ++jj) { x0[jj]=(__bf16)fl[jj]; x1[jj]=(__bf16)fl[8+jj]; }
        } else if constexpr (MODE == 1) {
            const __bf16* arow = (const __bf16*)actsrc + (size_t)nr * KP;
            x0 = *(const bf16x8*)(arow + kb16);
            x1 = *(const bf16x8*)(arow + kb16 + 8);
        } else {
            const int s = (nr < BATCH) ? nr : nr - BATCH;
            const int d = nr + BATCH * ((nr < BATCH) ? 1 : 1) + ((nr < BATCH) ? 0 : 0);
            // d_idx = nr + 2000 in both cases
            const __bf16* eb = (const __bf16*)actsrc;
            const __bf16* src = (kb16 < 176) ? (eb + (size_t)s * 176 + kb16)
                                             : (eb + (size_t)(nr + BATCH) * 176 + (kb16 - 176));
            x0 = *(const bf16x8*)src;
            x1 = *(const bf16x8*)(src + 8);
        }
        *(bf16x8*)&Ws[xrow][xhalf * 16]     = w0;
        *(bf16x8*)&Ws[xrow][xhalf * 16 + 8] = w1;
        *(bf16x8*)&Xs[xrow][xhalf * 16]     = x0;
        *(bf16x8*)&Xs[xrow][xhalf * 16 + 8] = x1;
        __syncthreads();

        bf16x8 af[4], bx_[4];
#pragma unroll
        for (int i = 0; i < 4; ++i) {
            af[i]  = *(const bf16x8*)&Ws[wm * 64 + i * 16 + lo][hi * 8];
            bx_[i] = *(const bf16x8*)&Xs[wn * 64 + i * 16 + lo][hi * 8];
        }
#pragma unroll
        for (int mi = 0; mi < 4; ++mi)
#pragma unroll
            for (int ni = 0; ni < 4; ++ni)
                acc[mi][ni] = __builtin_amdgcn_mfma_f32_16x16x32_bf16(
                    af[mi], bx_[ni], acc[mi][ni], 0, 0, 0);
        __syncthreads();
    }

#pragma unroll
    for (int mi = 0; mi < 4; ++mi) {
        const int jb = j0 + wm * 64 + mi * 16 + hi * 4;
        if (jb + 3 >= jmax) continue;
        const float4 b4 = *(const float4*)(bias + jb);
#pragma unroll
        for (int ni = 0; ni < 4; ++ni) {
            const int n = n0 + wn * 64 + ni * 16 + lo;
            if (n >= nrows) continue;
            float v0 = acc[mi][ni][0] + b4.x;
            float v1 = acc[mi][ni][1] + b4.y;
            float v2 = acc[mi][ni][2] + b4.z;
            float v3 = acc[mi][ni][3] + b4.w;
            if (relu) {
                v0 = fmaxf(v0, 0.f); v1 = fmaxf(v1, 0.f);
                v2 = fmaxf(v2, 0.f); v3 = fmaxf(v3, 0.f);
            }
            bf16x4 o;
            o[0]=(__bf16)v0; o[1]=(__bf16)v1; o[2]=(__bf16)v2; o[3]=(__bf16)v3;
            *(bf16x4*)(outb + (size_t)n * ostride + jb) = o;
        }
    }
}

// ============================================================
// Kernel 3: scores + softmax + ctx -> cat rows [ctx|pad|src|pad] bf16
// ============================================================
__global__ __launch_bounds__(256) void attn_mid_kernel(
    const float* __restrict__ mem_upd, const __bf16* __restrict__ kv,
    const __bf16* __restrict__ qb, const int* __restrict__ neighbors,
    const int* __restrict__ nodes_cat, __bf16* __restrict__ cat)
{
    __shared__ __align__(16) __bf16 kvs[KNBR][KVS];
    __shared__ float qs[176];
    __shared__ float scl[2][KNBR];
    __shared__ float attnl[2][KNBR];
    __shared__ int   nbrs[KNBR];

    const int i = blockIdx.x;
    const int t = threadIdx.x;

    if (t < KNBR) nbrs[t] = neighbors[i * KNBR + t];
    if (t < 176) qs[t] = (float)qb[(size_t)i * 176 + t];
    {
        const uint4* src = (const uint4*)(kv + (size_t)i * KNBR * KVS);
        uint4* dst = (uint4*)&kvs[0][0];
        for (int idx = t; idx < KNBR * KVS / 8; idx += 256) dst[idx] = src[idx];
    }
    __syncthreads();

    if (t < 2 * KNBR) {
        int h = t / KNBR, kn = t - h * KNBR;
        float s = 0.f;
#pragma unroll 2
        for (int j = 0; j < DH; ++j)
            s = fmaf(qs[h * DH + j], (float)kvs[kn][h * DH + j], s);
        s /= sqrtf((float)DH);
        scl[h][kn] = (nbrs[kn] > 0) ? s : -1e9f;
    }
    __syncthreads();
    if (t < 2) {
        float m = -INFINITY;
        for (int kn = 0; kn < KNBR; ++kn) m = fmaxf(m, scl[t][kn]);
        float se = 0.f;
        for (int kn = 0; kn < KNBR; ++kn) se += expf(scl[t][kn] - m);
        float inv = 1.f / se;
        for (int kn = 0; kn < KNBR; ++kn) attnl[t][kn] = expf(scl[t][kn] - m) * inv;
    }
    __syncthreads();
    if (t < DF) {
        int h = t / DH;
        float cx = 0.f;
#pragma unroll
        for (int kn = 0; kn < KNBR; ++kn)
            cx = fmaf(attnl[h][kn], (float)kvs[kn][176 + t], cx);
        cat[(size_t)i * 352 + t] = (__bf16)cx;
        cat[(size_t)i * 352 + 176 + t] =
            (__bf16)mem_upd[(size_t)nodes_cat[i] * DF + t];
    }
    if (t < 4) {
        cat[(size_t)i * 352 + 172 + t] = (__bf16)0.f;
        cat[(size_t)i * 352 + 348 + t] = (__bf16)0.f;
    }
}

// ============================================================
// Kernel 4: aff final: prob = sigmoid(aff_w2 . ah + b2)  (4000 rows)
// ============================================================
__global__ __launch_bounds__(256) void aff_fin_kernel(
    const __bf16* __restrict__ ah, const float* __restrict__ aff_w2,
    const float* __restrict__ aff_b2, float* __restrict__ out)
{
    const int t = threadIdx.x;
    const int w = t >> 6, lane = t & 63;
    const int row = blockIdx.x * 4 + w;
    if (row >= 2 * BATCH) return;
    float s = 0.f;
    if (lane < DF)       s += (float)ah[(size_t)row * 176 + lane] * aff_w2[lane];
    if (lane + 64 < DF)  s += (float)ah[(size_t)row * 176 + lane + 64] * aff_w2[lane + 64];
    if (lane + 128 < DF) s += (float)ah[(size_t)row * 176 + lane + 128] * aff_w2[lane + 128];
#pragma unroll
    for (int off = 32; off > 0; off >>= 1) s += __shfl_down(s, off, 64);
    if (lane == 0) out[row] = 1.f / (1.f + expf(-(s + aff_b2[0])));
}

// ============================================================
extern "C" void kernel_launch(void* const* d_in, const int* in_sizes, int n_in,
                              void* d_out, int out_size, void* d_ws, size_t ws_size,
                              hipStream_t stream)
{
    (void)in_sizes; (void)n_in; (void)out_size; (void)ws_size;
    const float* memory         = (const float*)d_in[0];
    const float* messages       = (const float*)d_in[1];
    const float* edge_features  = (const float*)d_in[2];
    const float* edge_times     = (const float*)d_in[3];
    const float* neighbor_times = (const float*)d_in[4];
    const float* time_w         = (const float*)d_in[5];
    const float* time_b         = (const float*)d_in[6];
    const float* gru_w_ih       = (const float*)d_in[7];
    const float* gru_w_hh       = (const float*)d_in[8];
    const float* gru_b_ih       = (const float*)d_in[9];
    const float* gru_b_hh       = (const float*)d_in[10];
    const float* w_q            = (const float*)d_in[11];
    const float* w_k            = (const float*)d_in[12];
    const float* w_v            = (const float*)d_in[13];
    const float* w_o            = (const float*)d_in[14];
    const float* merge_w1       = (const float*)d_in[15];
    const float* merge_b1       = (const float*)d_in[16];
    const float* merge_w2       = (const float*)d_in[17];
    const float* merge_b2       = (const float*)d_in[18];
    const float* aff_w1         = (const float*)d_in[19];
    const float* aff_b1         = (const float*)d_in[20];
    const float* aff_w2         = (const float*)d_in[21];
    const float* aff_b2         = (const float*)d_in[22];
    const int* src_nodes        = (const int*)d_in[23];
    const int* dst_nodes        = (const int*)d_in[24];
    const int* neg_nodes        = (const int*)d_in[25];
    const int* neighbors        = (const int*)d_in[26];
    const int* nbr_eidx         = (const int*)d_in[27];

    float* ws       = (float*)d_ws;
    __bf16* wpb     = (__bf16*)(ws + WPB_OFF);
    float* bp4      = ws + BP4_OFF;
    __bf16* wkvb    = (__bf16*)(ws + WKV_OFF);
    float* mem_upd  = ws + MU_OFF;
    __bf16* xbuf    = (__bf16*)(ws + UNI_OFF);
    __bf16* kv      = (__bf16*)(ws + KV_OFF);
    __bf16* qbuf    = (__bf16*)(ws + QB_OFF);
    __bf16* cat     = (__bf16*)(ws + CAT_OFF);
    __bf16* h1      = (__bf16*)(ws + H1_OFF);
    __bf16* embb    = (__bf16*)(ws + EMBB_OFF);
    __bf16* ah      = (__bf16*)(ws + AH_OFF);
    float* mw1o     = ws + MW1O_OFF;
    __bf16* wqb     = (__bf16*)(ws + WQB_OFF);
    __bf16* wm1b    = (__bf16*)(ws + WM1B_OFF);
    __bf16* wm2b    = (__bf16*)(ws + WM2B_OFF);
    __bf16* waffb   = (__bf16*)(ws + WAFFB_OFF);
    float* bm1p     = ws + BM1P_OFF;
    float* bm2p     = ws + BM2P_OFF;
    float* baffp    = ws + BAFFP_OFF;
    float* bq0      = ws + BQ0_OFF;
    int*   nodes_cat= (int*)(ws + NODES_OFF);
    float* out      = (float*)d_out;

    prep_kernel<<<(JP * KA + 255) / 256, 256, 0, stream>>>(
        gru_w_ih, gru_w_hh, gru_b_ih, gru_b_hh, wpb, bp4);
    prep_kv_kernel<<<(JKV * KP_KV + 255) / 256, 256, 0, stream>>>(w_k, w_v, wkvb);
    conv_kernel<<<2048, 256, 0, stream>>>(messages, memory, xbuf);
    gru_mfma2_kernel<<<NWG_GRU, 256, 0, stream>>>(xbuf, wpb, bp4, memory, mem_upd);
    // tail statics live in the (now dead) Xb region
    mw1o_kernel<<<(DF * DF + 255) / 256, 256, 0, stream>>>(merge_w1, w_o, mw1o);
    prep_tail_kernel<<<(192 * 352 + 255) / 256, 256, 0, stream>>>(
        w_q, mw1o, merge_w1, merge_w2, aff_w1, merge_b1, merge_b2, aff_b1,
        src_nodes, dst_nodes, neg_nodes,
        wqb, wm1b, wm2b, waffb, bm1p, bm2p, baffp, bq0, nodes_cat);
    kv_gemm_kernel<<<NKV_TILES * 3, 256, 0, stream>>>(
        mem_upd, edge_features, edge_times, neighbor_times, time_w, time_b,
        neighbors, nbr_eidx, wkvb, kv);
    tail_gemm_kernel<0, 352><<<47 * 2, 256, 0, stream>>>(
        wqb, bq0, mem_upd, time_b, nodes_cat, qbuf, 176, 176, M3, 0);
    attn_mid_kernel<<<M3, 256, 0, stream>>>(
        mem_upd, kv, qbuf, neighbors, nodes_cat, cat);
    tail_gemm_kernel<1, 352><<<47 * 2, 256, 0, stream>>>(
        wm1b, bm1p, cat, nullptr, nullptr, h1, 192, 192, M3, 1);
    tail_gemm_kernel<1, 192><<<47 * 2, 256, 0, stream>>>(
        wm2b, bm2p, h1, nullptr, nullptr, embb, 176, 176, M3, 0);
    tail_gemm_kernel<2, 352><<<32 * 2, 256, 0, stream>>>(
        waffb, baffp, embb, nullptr, nullptr, ah, 176, 176, 2 * BATCH, 1);
    aff_fin_kernel<<<(2 * BATCH + 3) / 4, 256, 0, stream>>>(ah, aff_w2, aff_b2, out);
}

// Round 6
// 763.466 us; speedup vs baseline: 8.5638x; 1.2054x over previous
//
#include <hip/hip_runtime.h>
#include <math.h>

// ---------------- problem constants ----------------
#define N_NODES 100000
#define BATCH   2000
#define KNBR    20
#define DF      172
#define MSGD    688
#define M3      6000
#define DH      86
#define KIN_D   516

// GRU GEMM
#define KA      864
#define JP      768
#define KREAL   860
#define NTILES_N ((N_NODES + 127) / 128)   // 782
#define NWG_GRU (NTILES_N * 6)             // 4692
#define KSTEPS  (KA / 32)                  // 27

// KV GEMM
#define NKV     120000
#define KP_KV   544
#define JKV     384
#define KVS     352
#define NKV_TILES ((NKV + 127) / 128)

typedef __bf16 bf16x8 __attribute__((ext_vector_type(8)));
typedef __bf16 bf16x4 __attribute__((ext_vector_type(4)));
typedef float  f32x4  __attribute__((ext_vector_type(4)));

// ---------------- ws layout (floats) ----------------
#define WPB_OFF   0
#define BP4_OFF   331776
#define WKV_OFF   332544
#define MU_OFF    436992
#define UNI_OFF   17636992          // Xb region (dead after gru); unions below
#define KV_OFF    UNI_OFF
#define QB_OFF    38756992
#define CAT_OFF   39286400
#define H1_OFF    40345216
#define EMBB_OFF  40922752
#define AH_OFF    41452160
#define MW1O_OFF  41812608
#define WQB_OFF   41842192
#define WM1B_OFF  41875984
#define WM2B_OFF  41909776
#define WAFFB_OFF 41928208
#define BM1P_OFF  41962000
#define BM2P_OFF  41962192
#define BAFFP_OFF 41962384
#define BQ0_OFF   41962576
#define NODES_OFF 41962768

__device__ __forceinline__ float sigmoidf_(float x) { return 1.0f / (1.0f + expf(-x)); }

typedef __attribute__((address_space(1))) const void gvoid;
typedef __attribute__((address_space(3))) void svoid;
__device__ __forceinline__ void gl16(const void* g, void* l) {
    __builtin_amdgcn_global_load_lds((gvoid*)g, (svoid*)l, 16, 0, 0);
}

// ============================================================
// Kernel 0a: gate-major bf16 GRU weight W' (JP x KA) + fused bias
// ============================================================
__global__ __launch_bounds__(256) void prep_kernel(
    const float* __restrict__ w_ih, const float* __restrict__ w_hh,
    const float* __restrict__ b_ih, const float* __restrict__ b_hh,
    __bf16* __restrict__ wpb, float* __restrict__ bp4)
{
    int idx = blockIdx.x * 256 + threadIdx.x;
    if (idx < JP * KA) {
        int j = idx / KA, k = idx - j * KA;
        int d = j >> 2, g = j & 3;
        float v = 0.f;
        if (d < DF) {
            if (g == 0) {
                if (k < MSGD) v = w_ih[d * MSGD + k];
                else if (k < KREAL) v = w_hh[d * DF + (k - MSGD)];
            } else if (g == 1) {
                if (k < MSGD) v = w_ih[(d + DF) * MSGD + k];
                else if (k < KREAL) v = w_hh[(d + DF) * DF + (k - MSGD)];
            } else if (g == 2) {
                if (k < MSGD) v = w_ih[(d + 2 * DF) * MSGD + k];
            } else {
                if (k >= MSGD && k < KREAL) v = w_hh[(d + 2 * DF) * DF + (k - MSGD)];
            }
        }
        wpb[idx] = (__bf16)v;
    }
    if (idx < JP) {
        int d = idx >> 2, g = idx & 3;
        float b = 0.f;
        if (d < DF) {
            if (g == 0) b = b_ih[d] + b_hh[d];
            else if (g == 1) b = b_ih[d + DF] + b_hh[d + DF];
            else if (g == 2) b = b_ih[d + 2 * DF];
            else            b = b_hh[d + 2 * DF];
        }
        bp4[idx] = b;
    }
}

// ============================================================
// Kernel 0b: combined bf16 KV weight (JKV x KP_KV)
// ============================================================
__global__ __launch_bounds__(256) void prep_kv_kernel(
    const float* __restrict__ w_k, const float* __restrict__ w_v,
    __bf16* __restrict__ wkvb)
{
    int idx = blockIdx.x * 256 + threadIdx.x;
    if (idx < JKV * KP_KV) {
        int j = idx / KP_KV, k = idx - j * KP_KV;
        float v = 0.f;
        if (k < KIN_D) {
            if (j < DF) v = w_k[j * KIN_D + k];
            else if (j >= 192 && j < 192 + DF) v = w_v[(j - 192) * KIN_D + k];
        }
        wkvb[idx] = (__bf16)v;
    }
}

// ============================================================
// Kernel 0c: X -> bf16
// ============================================================
__global__ __launch_bounds__(256) void conv_kernel(
    const float* __restrict__ messages, const float* __restrict__ memory,
    __bf16* __restrict__ xb)
{
    const long total = (long)N_NODES * (KA / 8);
    for (long idx = (long)blockIdx.x * 256 + threadIdx.x; idx < total;
         idx += (long)gridDim.x * 256) {
        const int r  = (int)(idx / (KA / 8));
        const int k  = (int)(idx - (long)r * (KA / 8)) * 8;
        float f[8];
        if (k < MSGD) {
            const float4 a = *(const float4*)(messages + (size_t)r * MSGD + k);
            const float4 b = *(const float4*)(messages + (size_t)r * MSGD + k + 4);
            f[0]=a.x; f[1]=a.y; f[2]=a.z; f[3]=a.w;
            f[4]=b.x; f[5]=b.y; f[6]=b.z; f[7]=b.w;
        } else {
            const int o = k - MSGD;
            const float4 a = *(const float4*)(memory + (size_t)r * DF + o);
            float4 b = make_float4(0.f, 0.f, 0.f, 0.f);
            if (o <= 164) b = *(const float4*)(memory + (size_t)r * DF + o + 4);
            f[0]=a.x; f[1]=a.y; f[2]=a.z; f[3]=a.w;
            f[4]=b.x; f[5]=b.y; f[6]=b.z; f[7]=b.w;
        }
        bf16x8 v;
#pragma unroll
        for (int j = 0; j < 8; ++j) v[j] = (__bf16)f[j];
        *(bf16x8*)(xb + (size_t)r * KA + k) = v;
    }
}

// ============================================================
// Kernel 0d: mw1o = merge_w1[:, :172] @ w_o   (172x172 f32)
// ============================================================
__global__ __launch_bounds__(256) void mw1o_kernel(
    const float* __restrict__ merge_w1, const float* __restrict__ w_o,
    float* __restrict__ mw1o)
{
    int idx = blockIdx.x * 256 + threadIdx.x;
    if (idx >= DF * DF) return;
    int j = idx / DF, k = idx - j * DF;
    float s = 0.f;
    for (int c = 0; c < DF; ++c)
        s = fmaf(merge_w1[j * 344 + c], w_o[c * DF + k], s);
    mw1o[idx] = s;
}

// ============================================================
// Kernel 0e: tail weights/biases/nodes_cat
// ============================================================
__global__ __launch_bounds__(256) void prep_tail_kernel(
    const float* __restrict__ w_q, const float* __restrict__ mw1o,
    const float* __restrict__ merge_w1, const float* __restrict__ merge_w2,
    const float* __restrict__ aff_w1,
    const float* __restrict__ merge_b1, const float* __restrict__ merge_b2,
    const float* __restrict__ aff_b1,
    const int* __restrict__ src_nodes, const int* __restrict__ dst_nodes,
    const int* __restrict__ neg_nodes,
    __bf16* __restrict__ wqb, __bf16* __restrict__ wm1b,
    __bf16* __restrict__ wm2b, __bf16* __restrict__ waffb,
    float* __restrict__ bm1p, float* __restrict__ bm2p,
    float* __restrict__ baffp, float* __restrict__ bq0,
    int* __restrict__ nodes_cat)
{
    int idx = blockIdx.x * 256 + threadIdx.x;
    if (idx < 192 * 352) {
        int j = idx / 352, k = idx - j * 352;
        float vq = 0.f, vm = 0.f, va = 0.f;
        if (j < DF) {
            if (k < DF) {
                vq = w_q[j * 344 + k];
                vm = mw1o[j * DF + k];
                va = aff_w1[j * 344 + k];
            } else if (k >= 176 && k < 348) {
                vq = w_q[j * 344 + 172 + (k - 176)];
                vm = merge_w1[j * 344 + 172 + (k - 176)];
                va = aff_w1[j * 344 + 172 + (k - 176)];
            }
        }
        wqb[idx] = (__bf16)vq;
        wm1b[idx] = (__bf16)vm;
        waffb[idx] = (__bf16)va;
    }
    if (idx < 192 * 192) {
        int j = idx / 192, k = idx - j * 192;
        wm2b[idx] = (__bf16)((j < DF && k < DF) ? merge_w2[j * DF + k] : 0.f);
    }
    if (idx < 192) {
        bm1p[idx]  = (idx < DF) ? merge_b1[idx] : 0.f;
        bm2p[idx]  = (idx < DF) ? merge_b2[idx] : 0.f;
        baffp[idx] = (idx < DF) ? aff_b1[idx] : 0.f;
        bq0[idx]   = 0.f;
    }
    if (idx < 6016) {
        int i = min(idx, M3 - 1);
        int node;
        if (i < BATCH)          node = src_nodes[i];
        else if (i < 2 * BATCH) node = dst_nodes[i - BATCH];
        else                    node = neg_nodes[i - 2 * BATCH];
        nodes_cat[idx] = node;
    }
}

// ============================================================
// Kernel 1: MFMA GRU GEMM v3 — 3-deep global_load_lds pipeline.
//  Counted vmcnt(4) (never 0 in steady state), raw s_barrier (no
//  compiler vmcnt(0) drain), STAGE issued 2 tiles ahead.
//  Safety: wait(vmcnt) BEFORE barrier -> after barrier every wave knows
//  tile ks landed; STAGE(ks+2) AFTER barrier overwrites buf used at
//  ks-1, legal because passing barrier ks implies MFMA(ks-1) issued
//  (its ds_reads lgkm-complete by data dependence).
// ============================================================
__global__ __launch_bounds__(256) void gru_mfma3_kernel(
    const __bf16* __restrict__ xb, const __bf16* __restrict__ wpb,
    const float* __restrict__ bp4, const float* __restrict__ memory,
    float* __restrict__ mem_upd)
{
    __shared__ __align__(16) __bf16 Ws[3][128 * 32];   // 24 KB
    __shared__ __align__(16) __bf16 Xs[3][128 * 32];   // 24 KB

    const int t    = threadIdx.x;
    const int w    = t >> 6, lane = t & 63;
    const int lo   = lane & 15, hi = lane >> 4;
    const int wm   = w >> 1, wn = w & 1;

    const int orig = blockIdx.x;
    const int q = NWG_GRU >> 3, rr = NWG_GRU & 7;
    const int xcd = orig & 7, oidx = orig >> 3;
    const int wgid = (xcd < rr ? xcd * (q + 1) : rr * (q + 1) + (xcd - rr) * q) + oidx;
    const int m_tile = wgid % 6;
    const int n_tile = wgid / 6;
    const int n0 = n_tile * 128;
    const int j0 = m_tile * 128;

    const int srow  = lane >> 2;
    const int sslot = ((lane & 3) ^ ((lane >> 3) & 3)) * 8;

    f32x4 acc[4][4];
#pragma unroll
    for (int mi = 0; mi < 4; ++mi)
#pragma unroll
        for (int ni = 0; ni < 4; ++ni)
            acc[mi][ni] = (f32x4){0.f, 0.f, 0.f, 0.f};

    const __bf16* wbase = wpb + (size_t)j0 * KA;
    const __bf16* xbase = xb + (size_t)n0 * KA;

#define STAGE(buf, k0)                                                          \
    {                                                                           \
        _Pragma("unroll")                                                       \
        for (int qq = 0; qq < 2; ++qq) {                                        \
            const int lr = w * 32 + qq * 16 + srow;                             \
            gl16(wbase + (size_t)lr * KA + (k0) + sslot,                        \
                 &Ws[buf][(w * 32 + qq * 16) * 32]);                            \
            gl16(xbase + (size_t)lr * KA + (k0) + sslot,                        \
                 &Xs[buf][(w * 32 + qq * 16) * 32]);                            \
        }                                                                       \
    }

    STAGE(0, 0);
    STAGE(1, 32);

    const int fsa = (hi ^ ((lo >> 1) & 3)) * 8;
    for (int ks = 0; ks < KSTEPS; ++ks) {
        // drain oldest STAGE (tile ks); keep the newer one in flight
        if (ks < KSTEPS - 1) {
            asm volatile("s_waitcnt vmcnt(4)" ::: "memory");
        } else {
            asm volatile("s_waitcnt vmcnt(0)" ::: "memory");
        }
        __builtin_amdgcn_s_barrier();
        if (ks + 2 < KSTEPS) STAGE((ks + 2) % 3, (ks + 2) * 32);

        const int bi = ks % 3;
        bf16x8 af[4], bx_[4];
#pragma unroll
        for (int i = 0; i < 4; ++i) {
            af[i]  = *(const bf16x8*)&Ws[bi][(wm * 64 + i * 16 + lo) * 32 + fsa];
            bx_[i] = *(const bf16x8*)&Xs[bi][(wn * 64 + i * 16 + lo) * 32 + fsa];
        }
#pragma unroll
        for (int mi = 0; mi < 4; ++mi)
#pragma unroll
            for (int ni = 0; ni < 4; ++ni)
                acc[mi][ni] = __builtin_amdgcn_mfma_f32_16x16x32_bf16(
                    af[mi], bx_[ni], acc[mi][ni], 0, 0, 0);
    }
#undef STAGE

    const int dbase = m_tile * 32 + wm * 16;
#pragma unroll
    for (int mi = 0; mi < 4; ++mi) {
        const int d = dbase + mi * 4 + hi;
        if (d >= DF) continue;
        const float4 b4 = *(const float4*)&bp4[4 * d];
#pragma unroll
        for (int ni = 0; ni < 4; ++ni) {
            const int n = n0 + wn * 64 + ni * 16 + lo;
            if (n >= N_NODES) continue;
            float sr  = acc[mi][ni][0] + b4.x;
            float sz  = acc[mi][ni][1] + b4.y;
            float gin = acc[mi][ni][2] + b4.z;
            float ghn = acc[mi][ni][3] + b4.w;
            float mem = memory[(size_t)n * DF + d];
            float rg  = sigmoidf_(sr);
            float zg  = sigmoidf_(sz);
            float nt  = tanhf(fmaf(rg, ghn, gin));
            mem_upd[(size_t)n * DF + d] = fmaf(zg, mem - nt, nt);
        }
    }
}

// ============================================================
// Kernel 2: K/V projection GEMM v2 — register prefetch (T14).
//  Next K-step's gathered loads issued right after this step's
//  ds_write, consumed next iteration (latency hides under MFMA).
//  Raw s_barrier + explicit lgkmcnt(0) so the barrier does not
//  drain the in-flight prefetch loads.
// ============================================================
__global__ __launch_bounds__(256) void kv_gemm2_kernel(
    const float* __restrict__ mem_upd, const float* __restrict__ edge_features,
    const float* __restrict__ edge_times, const float* __restrict__ neighbor_times,
    const float* __restrict__ time_w, const float* __restrict__ time_b,
    const int* __restrict__ neighbors, const int* __restrict__ nbr_eidx,
    const __bf16* __restrict__ wkvb, __bf16* __restrict__ kv)
{
    __shared__ __align__(16) __bf16 Ws[128][32];
    __shared__ __align__(16) __bf16 Xs[128][32];

    const int t    = threadIdx.x;
    const int w    = t >> 6, lane = t & 63;
    const int lo   = lane & 15, hi = lane >> 4;
    const int wm   = w >> 1, wn = w & 1;

    const int bx     = blockIdx.x;
    const int n_tile = bx / 3;
    const int m_tile = bx - n_tile * 3;
    const int n0     = n_tile * 128;
    const int j0     = m_tile * 128;

    const int xrow  = t >> 1, xhalf = t & 1;
    const int nr    = min(n0 + xrow, NKV - 1);
    const int nbr   = neighbors[nr];
    const int eidx  = nbr_eidx[nr];
    const float dt  = edge_times[(nr / KNBR) % BATCH] - neighbor_times[nr];
    const float* mrow = mem_upd       + (size_t)nbr  * DF;
    const float* erow = edge_features + (size_t)eidx * DF;
    const __bf16* wrow = wkvb + (size_t)(j0 + xrow) * KP_KV;

    f32x4 acc[4][4];
#pragma unroll
    for (int mi = 0; mi < 4; ++mi)
#pragma unroll
        for (int ni = 0; ni < 4; ++ni)
            acc[mi][ni] = (f32x4){0.f, 0.f, 0.f, 0.f};

#define LOADX(k0, dst)                                                          \
    {                                                                           \
        _Pragma("unroll")                                                       \
        for (int c = 0; c < 4; ++c) {                                           \
            const int kb = (k0) + xhalf * 16 + c * 4;                           \
            float4 v;                                                           \
            if (kb < DF) {                                                      \
                v = *(const float4*)(mrow + kb);                                \
            } else if (kb < 2 * DF) {                                           \
                v = *(const float4*)(erow + (kb - DF));                         \
            } else if (kb < KIN_D) {                                            \
                const float4 tw = *(const float4*)(time_w + (kb - 2 * DF));     \
                const float4 tb = *(const float4*)(time_b + (kb - 2 * DF));     \
                v.x = cosf(fmaf(dt, tw.x, tb.x));                               \
                v.y = cosf(fmaf(dt, tw.y, tb.y));                               \
                v.z = cosf(fmaf(dt, tw.z, tb.z));                               \
                v.w = cosf(fmaf(dt, tw.w, tb.w));                               \
            } else {                                                            \
                v = make_float4(0.f, 0.f, 0.f, 0.f);                            \
            }                                                                   \
            dst[c] = v;                                                         \
        }                                                                       \
    }

    float4 xf[4];
    bf16x8 wp0, wp1;
    LOADX(0, xf);
    wp0 = *(const bf16x8*)(wrow + xhalf * 16);
    wp1 = *(const bf16x8*)(wrow + xhalf * 16 + 8);

    for (int ks = 0; ks < KP_KV / 32; ++ks) {
        const int k0 = ks * 32;
        // convert prefetched regs, write LDS
        bf16x8 x0, x1;
        x0[0]=(__bf16)xf[0].x; x0[1]=(__bf16)xf[0].y; x0[2]=(__bf16)xf[0].z; x0[3]=(__bf16)xf[0].w;
        x0[4]=(__bf16)xf[1].x; x0[5]=(__bf16)xf[1].y; x0[6]=(__bf16)xf[1].z; x0[7]=(__bf16)xf[1].w;
        x1[0]=(__bf16)xf[2].x; x1[1]=(__bf16)xf[2].y; x1[2]=(__bf16)xf[2].z; x1[3]=(__bf16)xf[2].w;
        x1[4]=(__bf16)xf[3].x; x1[5]=(__bf16)xf[3].y; x1[6]=(__bf16)xf[3].z; x1[7]=(__bf16)xf[3].w;
        *(bf16x8*)&Ws[xrow][xhalf * 16]     = wp0;
        *(bf16x8*)&Ws[xrow][xhalf * 16 + 8] = wp1;
        *(bf16x8*)&Xs[xrow][xhalf * 16]     = x0;
        *(bf16x8*)&Xs[xrow][xhalf * 16 + 8] = x1;

        // issue next-step gathers now; they complete under the MFMAs below
        if (ks + 1 < KP_KV / 32) {
            LOADX(k0 + 32, xf);
            wp0 = *(const bf16x8*)(wrow + k0 + 32 + xhalf * 16);
            wp1 = *(const bf16x8*)(wrow + k0 + 32 + xhalf * 16 + 8);
        }

        asm volatile("s_waitcnt lgkmcnt(0)" ::: "memory");   // ds_writes visible
        __builtin_amdgcn_s_barrier();

        bf16x8 af[4], bx_[4];
#pragma unroll
        for (int i = 0; i < 4; ++i) {
            af[i]  = *(const bf16x8*)&Ws[wm * 64 + i * 16 + lo][hi * 8];
            bx_[i] = *(const bf16x8*)&Xs[wn * 64 + i * 16 + lo][hi * 8];
        }
#pragma unroll
        for (int mi = 0; mi < 4; ++mi)
#pragma unroll
            for (int ni = 0; ni < 4; ++ni)
                acc[mi][ni] = __builtin_amdgcn_mfma_f32_16x16x32_bf16(
                    af[mi], bx_[ni], acc[mi][ni], 0, 0, 0);

        __builtin_amdgcn_s_barrier();   // all ds_reads done before next overwrite
    }
#undef LOADX

#pragma unroll
    for (int mi = 0; mi < 4; ++mi) {
        const int jb = j0 + wm * 64 + mi * 16 + hi * 4;
        int off;
        if (jb + 3 < DF)                 off = jb;
        else if (jb >= 192 && jb < 361)  off = jb - 16;
        else continue;
#pragma unroll
        for (int ni = 0; ni < 4; ++ni) {
            const int n = n0 + wn * 64 + ni * 16 + lo;
            if (n >= NKV) continue;
            bf16x4 o;
            o[0] = (__bf16)acc[mi][ni][0];
            o[1] = (__bf16)acc[mi][ni][1];
            o[2] = (__bf16)acc[mi][ni][2];
            o[3] = (__bf16)acc[mi][ni][3];
            *(bf16x4*)(kv + (size_t)n * KVS + off) = o;
        }
    }
}

// ============================================================
// Generic tail GEMM (unchanged from R5)
// ============================================================
template<int MODE, int KP>
__global__ __launch_bounds__(256) void tail_gemm_kernel(
    const __bf16* __restrict__ wb, const float* __restrict__ bias,
    const void* __restrict__ actsrc, const float* __restrict__ time_b,
    const int* __restrict__ nodes_cat,
    __bf16* __restrict__ outb, int ostride, int jmax, int nrows, int relu)
{
    __shared__ __align__(16) __bf16 Ws[128][32];
    __shared__ __align__(16) __bf16 Xs[128][32];

    const int t    = threadIdx.x;
    const int w    = t >> 6, lane = t & 63;
    const int lo   = lane & 15, hi = lane >> 4;
    const int wm   = w >> 1, wn = w & 1;

    const int n_tile = blockIdx.x >> 1;
    const int j0     = (blockIdx.x & 1) * 64;
    const int n0     = n_tile * 128;

    const int xrow  = t >> 1, xhalf = t & 1;
    const int nr    = min(n0 + xrow, nrows - 1);
    const __bf16* wrow = wb + (size_t)(j0 + xrow) * KP;

    f32x4 acc[4][4];
#pragma unroll
    for (int mi = 0; mi < 4; ++mi)
#pragma unroll
        for (int ni = 0; ni < 4; ++ni)
            acc[mi][ni] = (f32x4){0.f, 0.f, 0.f, 0.f};

    for (int k0 = 0; k0 < KP; k0 += 32) {
        bf16x8 w0 = *(const bf16x8*)(wrow + k0 + xhalf * 16);
        bf16x8 w1 = *(const bf16x8*)(wrow + k0 + xhalf * 16 + 8);
        bf16x8 x0, x1;
        const int kb16 = k0 + xhalf * 16;
        if constexpr (MODE == 0) {
            const float* mrow = (const float*)actsrc + (size_t)nodes_cat[nr] * DF;
            float fl[16];
#pragma unroll
            for (int c = 0; c < 4; ++c) {
                const int b = kb16 + c * 4;
                float4 v;
                if (b + 3 < DF) v = *(const float4*)(mrow + b);
                else if (b >= 176 && b < 348) {
                    const float4 tb = *(const float4*)(time_b + (b - 176));
                    v.x = cosf(tb.x); v.y = cosf(tb.y);
                    v.z = cosf(tb.z); v.w = cosf(tb.w);
                } else v = make_float4(0.f, 0.f, 0.f, 0.f);
                fl[c*4+0]=v.x; fl[c*4+1]=v.y; fl[c*4+2]=v.z; fl[c*4+3]=v.w;
            }
#pragma unroll
            for (int jj = 0; jj < 8; ++jj) { x0[jj]=(__bf16)fl[jj]; x1[jj]=(__bf16)fl[8+jj]; }
        } else if constexpr (MODE == 1) {
            const __bf16* arow = (const __bf16*)actsrc + (size_t)nr * KP;
            x0 = *(const bf16x8*)(arow + kb16);
            x1 = *(const bf16x8*)(arow + kb16 + 8);
        } else {
            const int s = (nr < BATCH) ? nr : nr - BATCH;
            const __bf16* eb = (const __bf16*)actsrc;
            const __bf16* src = (kb16 < 176) ? (eb + (size_t)s * 176 + kb16)
                                             : (eb + (size_t)(nr + BATCH) * 176 + (kb16 - 176));
            x0 = *(const bf16x8*)src;
            x1 = *(const bf16x8*)(src + 8);
        }
        *(bf16x8*)&Ws[xrow][xhalf * 16]     = w0;
        *(bf16x8*)&Ws[xrow][xhalf * 16 + 8] = w1;
        *(bf16x8*)&Xs[xrow][xhalf * 16]     = x0;
        *(bf16x8*)&Xs[xrow][xhalf * 16 + 8] = x1;
        __syncthreads();

        bf16x8 af[4], bx_[4];
#pragma unroll
        for (int i = 0; i < 4; ++i) {
            af[i]  = *(const bf16x8*)&Ws[wm * 64 + i * 16 + lo][hi * 8];
            bx_[i] = *(const bf16x8*)&Xs[wn * 64 + i * 16 + lo][hi * 8];
        }
#pragma unroll
        for (int mi = 0; mi < 4; ++mi)
#pragma unroll
            for (int ni = 0; ni < 4; ++ni)
                acc[mi][ni] = __builtin_amdgcn_mfma_f32_16x16x32_bf16(
                    af[mi], bx_[ni], acc[mi][ni], 0, 0, 0);
        __syncthreads();
    }

#pragma unroll
    for (int mi = 0; mi < 4; ++mi) {
        const int jb = j0 + wm * 64 + mi * 16 + hi * 4;
        if (jb + 3 >= jmax) continue;
        const float4 b4 = *(const float4*)(bias + jb);
#pragma unroll
        for (int ni = 0; ni < 4; ++ni) {
            const int n = n0 + wn * 64 + ni * 16 + lo;
            if (n >= nrows) continue;
            float v0 = acc[mi][ni][0] + b4.x;
            float v1 = acc[mi][ni][1] + b4.y;
            float v2 = acc[mi][ni][2] + b4.z;
            float v3 = acc[mi][ni][3] + b4.w;
            if (relu) {
                v0 = fmaxf(v0, 0.f); v1 = fmaxf(v1, 0.f);
                v2 = fmaxf(v2, 0.f); v3 = fmaxf(v3, 0.f);
            }
            bf16x4 o;
            o[0]=(__bf16)v0; o[1]=(__bf16)v1; o[2]=(__bf16)v2; o[3]=(__bf16)v3;
            *(bf16x4*)(outb + (size_t)n * ostride + jb) = o;
        }
    }
}

// ============================================================
// Kernel 3: scores + softmax + ctx -> cat rows (unchanged)
// ============================================================
__global__ __launch_bounds__(256) void attn_mid_kernel(
    const float* __restrict__ mem_upd, const __bf16* __restrict__ kv,
    const __bf16* __restrict__ qb, const int* __restrict__ neighbors,
    const int* __restrict__ nodes_cat, __bf16* __restrict__ cat)
{
    __shared__ __align__(16) __bf16 kvs[KNBR][KVS];
    __shared__ float qs[176];
    __shared__ float scl[2][KNBR];
    __shared__ float attnl[2][KNBR];
    __shared__ int   nbrs[KNBR];

    const int i = blockIdx.x;
    const int t = threadIdx.x;

    if (t < KNBR) nbrs[t] = neighbors[i * KNBR + t];
    if (t < 176) qs[t] = (float)qb[(size_t)i * 176 + t];
    {
        const uint4* src = (const uint4*)(kv + (size_t)i * KNBR * KVS);
        uint4* dst = (uint4*)&kvs[0][0];
        for (int idx = t; idx < KNBR * KVS / 8; idx += 256) dst[idx] = src[idx];
    }
    __syncthreads();

    if (t < 2 * KNBR) {
        int h = t / KNBR, kn = t - h * KNBR;
        float s = 0.f;
#pragma unroll 2
        for (int j = 0; j < DH; ++j)
            s = fmaf(qs[h * DH + j], (float)kvs[kn][h * DH + j], s);
        s /= sqrtf((float)DH);
        scl[h][kn] = (nbrs[kn] > 0) ? s : -1e9f;
    }
    __syncthreads();
    if (t < 2) {
        float m = -INFINITY;
        for (int kn = 0; kn < KNBR; ++kn) m = fmaxf(m, scl[t][kn]);
        float se = 0.f;
        for (int kn = 0; kn < KNBR; ++kn) se += expf(scl[t][kn] - m);
        float inv = 1.f / se;
        for (int kn = 0; kn < KNBR; ++kn) attnl[t][kn] = expf(scl[t][kn] - m) * inv;
    }
    __syncthreads();
    if (t < DF) {
        int h = t / DH;
        float cx = 0.f;
#pragma unroll
        for (int kn = 0; kn < KNBR; ++kn)
            cx = fmaf(attnl[h][kn], (float)kvs[kn][176 + t], cx);
        cat[(size_t)i * 352 + t] = (__bf16)cx;
        cat[(size_t)i * 352 + 176 + t] =
            (__bf16)mem_upd[(size_t)nodes_cat[i] * DF + t];
    }
    if (t < 4) {
        cat[(size_t)i * 352 + 172 + t] = (__bf16)0.f;
        cat[(size_t)i * 352 + 348 + t] = (__bf16)0.f;
    }
}

// ============================================================
// Kernel 4: aff final (unchanged)
// ============================================================
__global__ __launch_bounds__(256) void aff_fin_kernel(
    const __bf16* __restrict__ ah, const float* __restrict__ aff_w2,
    const float* __restrict__ aff_b2, float* __restrict__ out)
{
    const int t = threadIdx.x;
    const int w = t >> 6, lane = t & 63;
    const int row = blockIdx.x * 4 + w;
    if (row >= 2 * BATCH) return;
    float s = 0.f;
    if (lane < DF)       s += (float)ah[(size_t)row * 176 + lane] * aff_w2[lane];
    if (lane + 64 < DF)  s += (float)ah[(size_t)row * 176 + lane + 64] * aff_w2[lane + 64];
    if (lane + 128 < DF) s += (float)ah[(size_t)row * 176 + lane + 128] * aff_w2[lane + 128];
#pragma unroll
    for (int off = 32; off > 0; off >>= 1) s += __shfl_down(s, off, 64);
    if (lane == 0) out[row] = 1.f / (1.f + expf(-(s + aff_b2[0])));
}

// ============================================================
extern "C" void kernel_launch(void* const* d_in, const int* in_sizes, int n_in,
                              void* d_out, int out_size, void* d_ws, size_t ws_size,
                              hipStream_t stream)
{
    (void)in_sizes; (void)n_in; (void)out_size; (void)ws_size;
    const float* memory         = (const float*)d_in[0];
    const float* messages       = (const float*)d_in[1];
    const float* edge_features  = (const float*)d_in[2];
    const float* edge_times     = (const float*)d_in[3];
    const float* neighbor_times = (const float*)d_in[4];
    const float* time_w         = (const float*)d_in[5];
    const float* time_b         = (const float*)d_in[6];
    const float* gru_w_ih       = (const float*)d_in[7];
    const float* gru_w_hh       = (const float*)d_in[8];
    const float* gru_b_ih       = (const float*)d_in[9];
    const float* gru_b_hh       = (const float*)d_in[10];
    const float* w_q            = (const float*)d_in[11];
    const float* w_k            = (const float*)d_in[12];
    const float* w_v            = (const float*)d_in[13];
    const float* w_o            = (const float*)d_in[14];
    const float* merge_w1       = (const float*)d_in[15];
    const float* merge_b1       = (const float*)d_in[16];
    const float* merge_w2       = (const float*)d_in[17];
    const float* merge_b2       = (const float*)d_in[18];
    const float* aff_w1         = (const float*)d_in[19];
    const float* aff_b1         = (const float*)d_in[20];
    const float* aff_w2         = (const float*)d_in[21];
    const float* aff_b2         = (const float*)d_in[22];
    const int* src_nodes        = (const int*)d_in[23];
    const int* dst_nodes        = (const int*)d_in[24];
    const int* neg_nodes        = (const int*)d_in[25];
    const int* neighbors        = (const int*)d_in[26];
    const int* nbr_eidx         = (const int*)d_in[27];

    float* ws       = (float*)d_ws;
    __bf16* wpb     = (__bf16*)(ws + WPB_OFF);
    float* bp4      = ws + BP4_OFF;
    __bf16* wkvb    = (__bf16*)(ws + WKV_OFF);
    float* mem_upd  = ws + MU_OFF;
    __bf16* xbuf    = (__bf16*)(ws + UNI_OFF);
    __bf16* kv      = (__bf16*)(ws + KV_OFF);
    __bf16* qbuf    = (__bf16*)(ws + QB_OFF);
    __bf16* cat     = (__bf16*)(ws + CAT_OFF);
    __bf16* h1      = (__bf16*)(ws + H1_OFF);
    __bf16* embb    = (__bf16*)(ws + EMBB_OFF);
    __bf16* ah      = (__bf16*)(ws + AH_OFF);
    float* mw1o     = ws + MW1O_OFF;
    __bf16* wqb     = (__bf16*)(ws + WQB_OFF);
    __bf16* wm1b    = (__bf16*)(ws + WM1B_OFF);
    __bf16* wm2b    = (__bf16*)(ws + WM2B_OFF);
    __bf16* waffb   = (__bf16*)(ws + WAFFB_OFF);
    float* bm1p     = ws + BM1P_OFF;
    float* bm2p     = ws + BM2P_OFF;
    float* baffp    = ws + BAFFP_OFF;
    float* bq0      = ws + BQ0_OFF;
    int*   nodes_cat= (int*)(ws + NODES_OFF);
    float* out      = (float*)d_out;

    prep_kernel<<<(JP * KA + 255) / 256, 256, 0, stream>>>(
        gru_w_ih, gru_w_hh, gru_b_ih, gru_b_hh, wpb, bp4);
    prep_kv_kernel<<<(JKV * KP_KV + 255) / 256, 256, 0, stream>>>(w_k, w_v, wkvb);
    conv_kernel<<<2048, 256, 0, stream>>>(messages, memory, xbuf);
    gru_mfma3_kernel<<<NWG_GRU, 256, 0, stream>>>(xbuf, wpb, bp4, memory, mem_upd);
    mw1o_kernel<<<(DF * DF + 255) / 256, 256, 0, stream>>>(merge_w1, w_o, mw1o);
    prep_tail_kernel<<<(192 * 352 + 255) / 256, 256, 0, stream>>>(
        w_q, mw1o, merge_w1, merge_w2, aff_w1, merge_b1, merge_b2, aff_b1,
        src_nodes, dst_nodes, neg_nodes,
        wqb, wm1b, wm2b, waffb, bm1p, bm2p, baffp, bq0, nodes_cat);
    kv_gemm2_kernel<<<NKV_TILES * 3, 256, 0, stream>>>(
        mem_upd, edge_features, edge_times, neighbor_times, time_w, time_b,
        neighbors, nbr_eidx, wkvb, kv);
    tail_gemm_kernel<0, 352><<<47 * 2, 256, 0, stream>>>(
        wqb, bq0, mem_upd, time_b, nodes_cat, qbuf, 176, 176, M3, 0);
    attn_mid_kernel<<<M3, 256, 0, stream>>>(
        mem_upd, kv, qbuf, neighbors, nodes_cat, cat);
    tail_gemm_kernel<1, 352><<<47 * 2, 256, 0, stream>>>(
        wm1b, bm1p, cat, nullptr, nullptr, h1, 192, 192, M3, 1);
    tail_gemm_kernel<1, 192><<<47 * 2, 256, 0, stream>>>(
        wm2b, bm2p, h1, nullptr, nullptr, embb, 176, 176, M3, 0);
    tail_gemm_kernel<2, 352><<<32 * 2, 256, 0, stream>>>(
        waffb, baffp, embb, nullptr, nullptr, ah, 176, 176, 2 * BATCH, 1);
    aff_fin_kernel<<<(2 * BATCH + 3) / 4, 256, 0, stream>>>(ah, aff_w2, aff_b2, out);
}